// Round 1
// baseline (271.079 us; speedup 1.0000x reference)
//
#include <hip/hip_runtime.h>
#include <math.h>

#define DM 1024
#define NH 16
#define HD 64
#define SEQ 2048
#define NB2 2
#define MROWS 4096   // NB2*SEQ

typedef unsigned short u16;
typedef __attribute__((ext_vector_type(8))) short short8;
typedef __attribute__((ext_vector_type(4))) float f32x4;

static __device__ __forceinline__ u16 f2bf(float f) {
  union { float f; unsigned u; } v; v.f = f;
  unsigned r = v.u + 0x7fffu + ((v.u >> 16) & 1u);
  return (u16)(r >> 16);
}

static __device__ __forceinline__ short8 cvt8(float4 a, float4 b) {
  short8 s;
  s[0] = (short)f2bf(a.x); s[1] = (short)f2bf(a.y);
  s[2] = (short)f2bf(a.z); s[3] = (short)f2bf(a.w);
  s[4] = (short)f2bf(b.x); s[5] = (short)f2bf(b.y);
  s[6] = (short)f2bf(b.z); s[7] = (short)f2bf(b.w);
  return s;
}

__global__ void rope_table_kernel(float* __restrict__ cosT, float* __restrict__ sinT) {
  int idx = blockIdx.x * blockDim.x + threadIdx.x;
  if (idx >= SEQ * 32) return;
  int l = idx >> 5, i = idx & 31;
  float invf = expf(-(float)i * (9.210340371976184f / 32.0f)); // 10000^(-i/32)
  float ang = (float)l * invf;
  float s, c;
  sincosf(ang, &s, &c);
  cosT[idx] = c; sinT[idx] = s;
}

// C[4096][1024] = A[4096][1024] x W[1024][1024]^T (+bias)
// MODE 0: bf16 out. MODE 1: bf16 out, RoPE fused, *qscale. MODE 2: bf16 A input, f32 out.
template<int MODE>
__global__ __launch_bounds__(256) void gemm_bt(
    const float* __restrict__ Af, const u16* __restrict__ Ab,
    const float* __restrict__ W,
    const float* __restrict__ bias,
    u16* __restrict__ Cb, float* __restrict__ Cf,
    const float* __restrict__ cosT, const float* __restrict__ sinT,
    float qscale)
{
  // LDS layout [kchunk(0..3)][row(0..127)][8] : elem = kc*1024 + row*8 + j
  __shared__ __align__(16) u16 As[4096];
  __shared__ __align__(16) u16 Bs[4096];
  const int tid = threadIdx.x;
  const int lane = tid & 63;
  const int wid = tid >> 6;
  const int wr = wid >> 1, wc = wid & 1;
  const int row0 = blockIdx.x * 128, col0 = blockIdx.y * 128;
  const int fr = lane & 15, kg = lane >> 4;

  const int sr = tid >> 2;   // 0..63
  const int skc = tid & 3;   // 0..3

  u16* Al0 = &As[skc * 1024 + sr * 8];
  u16* Al1 = &As[skc * 1024 + (sr + 64) * 8];
  u16* Bl0 = &Bs[skc * 1024 + sr * 8];
  u16* Bl1 = &Bs[skc * 1024 + (sr + 64) * 8];

  const size_t aoff0 = (size_t)(row0 + sr) * DM + skc * 8;
  const size_t aoff1 = (size_t)(row0 + sr + 64) * DM + skc * 8;
  const size_t woff0 = (size_t)(col0 + sr) * DM + skc * 8;
  const size_t woff1 = (size_t)(col0 + sr + 64) * DM + skc * 8;

  f32x4 acc[4][4];
#pragma unroll
  for (int m = 0; m < 4; ++m)
#pragma unroll
    for (int n = 0; n < 4; ++n) acc[m][n] = (f32x4){0.f, 0.f, 0.f, 0.f};

  float4 paf0, paf1, paf2, paf3, pbf0, pbf1, pbf2, pbf3;
  short8 pab0, pab1;
  if (MODE == 2) {
    pab0 = *(const short8*)(Ab + aoff0);
    pab1 = *(const short8*)(Ab + aoff1);
  } else {
    paf0 = *(const float4*)(Af + aoff0); paf1 = *(const float4*)(Af + aoff0 + 4);
    paf2 = *(const float4*)(Af + aoff1); paf3 = *(const float4*)(Af + aoff1 + 4);
  }
  pbf0 = *(const float4*)(W + woff0); pbf1 = *(const float4*)(W + woff0 + 4);
  pbf2 = *(const float4*)(W + woff1); pbf3 = *(const float4*)(W + woff1 + 4);

  const int KT = DM / 32;
  for (int kt = 0; kt < KT; ++kt) {
    __syncthreads();
    if (MODE == 2) { *(short8*)Al0 = pab0; *(short8*)Al1 = pab1; }
    else { *(short8*)Al0 = cvt8(paf0, paf1); *(short8*)Al1 = cvt8(paf2, paf3); }
    *(short8*)Bl0 = cvt8(pbf0, pbf1);
    *(short8*)Bl1 = cvt8(pbf2, pbf3);
    __syncthreads();
    if (kt + 1 < KT) {
      const int off = (kt + 1) * 32;
      if (MODE == 2) {
        pab0 = *(const short8*)(Ab + aoff0 + off);
        pab1 = *(const short8*)(Ab + aoff1 + off);
      } else {
        paf0 = *(const float4*)(Af + aoff0 + off); paf1 = *(const float4*)(Af + aoff0 + off + 4);
        paf2 = *(const float4*)(Af + aoff1 + off); paf3 = *(const float4*)(Af + aoff1 + off + 4);
      }
      pbf0 = *(const float4*)(W + woff0 + off); pbf1 = *(const float4*)(W + woff0 + off + 4);
      pbf2 = *(const float4*)(W + woff1 + off); pbf3 = *(const float4*)(W + woff1 + off + 4);
    }
    short8 afr[4], bfr[4];
#pragma unroll
    for (int m = 0; m < 4; ++m)
      afr[m] = *(const short8*)(&As[kg * 1024 + (wr * 64 + m * 16 + fr) * 8]);
#pragma unroll
    for (int n = 0; n < 4; ++n)
      bfr[n] = *(const short8*)(&Bs[kg * 1024 + (wc * 64 + n * 16 + fr) * 8]);
#pragma unroll
    for (int m = 0; m < 4; ++m)
#pragma unroll
      for (int n = 0; n < 4; ++n)
        acc[m][n] = __builtin_amdgcn_mfma_f32_16x16x32_bf16(afr[m], bfr[n], acc[m][n], 0, 0, 0);
  }

  // epilogue: C row = row0 + wr*64 + m*16 + kg*4 + r ; col = col0 + wc*64 + n*16 + fr
#pragma unroll
  for (int m = 0; m < 4; ++m) {
#pragma unroll
    for (int r = 0; r < 4; ++r) {
      const int rowg = row0 + wr * 64 + m * 16 + kg * 4 + r;
      if (MODE == 2) {
#pragma unroll
        for (int n = 0; n < 4; ++n) {
          const int colg = col0 + wc * 64 + n * 16 + fr;
          Cf[(size_t)rowg * DM + colg] = acc[m][n][r] + bias[colg];
        }
      } else if (MODE == 0) {
#pragma unroll
        for (int n = 0; n < 4; ++n) {
          const int colg = col0 + wc * 64 + n * 16 + fr;
          Cb[(size_t)rowg * DM + colg] = f2bf(acc[m][n][r] + bias[colg]);
        }
      } else {
        const int l = rowg & (SEQ - 1);
#pragma unroll
        for (int n = 0; n < 4; ++n) {
          const int colg = col0 + wc * 64 + n * 16 + fr;
          const int i = n * 16 + fr;      // position within head (0..63)
          const int fi = i & 31;          // freq index
          const float c = cosT[l * 32 + fi];
          const float s = sinT[l * 32 + fi];
          const float v = acc[m][n][r] + bias[colg];
          const float pv = acc[m][n ^ 2][r] + bias[col0 + wc * 64 + (n ^ 2) * 16 + fr];
          const float o = v * c + ((i < 32) ? -pv : pv) * s;
          Cb[(size_t)rowg * DM + colg] = f2bf(o * qscale);
        }
      }
    }
  }
}

// Flash attention, causal. Block = (qb, h, n): 128 q-rows, 4 waves x 32 rows. KBLOCK=64.
__global__ __launch_bounds__(256) void flash_attn(
    const u16* __restrict__ Qp, const u16* __restrict__ Kp,
    const u16* __restrict__ Vp, u16* __restrict__ Op)
{
  __shared__ __align__(16) u16 Ks[4096];      // [dc(0..7)][s(0..63)][8]
  __shared__ __align__(16) u16 Vs[64 * 72];   // [s][72] padded row-major
  __shared__ __align__(16) u16 Vt[4096];      // [sc(0..7)][d(0..63)][8] : V^T mfma layout
  __shared__ __align__(16) u16 Ps[4 * 32 * 72]; // per-wave P tile [32][72]

  const int tid = threadIdx.x;
  const int lane = tid & 63;
  const int w = tid >> 6;
  const int fr = lane & 15, rg = lane >> 4;
  const int qb = blockIdx.x, h = blockIdx.y, nb = blockIdx.z;

  const size_t headoff = (size_t)nb * SEQ * DM + (size_t)h * HD;

  // Q fragments held for whole kernel: rows qb*128 + w*32 + m*16 + fr, k = ck*32 + rg*8 + j
  short8 qf[2][2];
#pragma unroll
  for (int m = 0; m < 2; ++m)
#pragma unroll
    for (int ck = 0; ck < 2; ++ck)
      qf[m][ck] = *(const short8*)(Qp + headoff +
          (size_t)(qb * 128 + w * 32 + m * 16 + fr) * DM + ck * 32 + rg * 8);

  f32x4 accO[2][4];
  float m_run[2][4], l_run[2][4];
#pragma unroll
  for (int m = 0; m < 2; ++m) {
#pragma unroll
    for (int df = 0; df < 4; ++df) accO[m][df] = (f32x4){0.f, 0.f, 0.f, 0.f};
#pragma unroll
    for (int r = 0; r < 4; ++r) { m_run[m][r] = -3e38f; l_run[m][r] = 0.f; }
  }

  const int rowmax_wave = qb * 128 + w * 32 + 31;
  const int KBend = qb * 2 + 2;
  const int ss = tid >> 3;    // 0..31
  const int sc8 = tid & 7;    // 16B chunk within row
  u16* Pw = &Ps[w * 2304];

  for (int kb = 0; kb < KBend; ++kb) {
    // ---- stage K rows + V rows ----
#pragma unroll
    for (int rep = 0; rep < 2; ++rep) {
      const int s = ss + rep * 32;
      const size_t g = headoff + (size_t)(kb * 64 + s) * DM + sc8 * 8;
      *(short8*)(&Ks[sc8 * 512 + s * 8]) = *(const short8*)(Kp + g);
      *(short8*)(&Vs[s * 72 + sc8 * 8]) = *(const short8*)(Vp + g);
    }
    __syncthreads();

    const bool active = (kb * 64) <= rowmax_wave;
    f32x4 sc_[2][4];
    if (active) {
      short8 kf[4][2];
#pragma unroll
      for (int sf = 0; sf < 4; ++sf)
#pragma unroll
        for (int ck = 0; ck < 2; ++ck)
          kf[sf][ck] = *(const short8*)(&Ks[(ck * 4 + rg) * 512 + (sf * 16 + fr) * 8]);
#pragma unroll
      for (int m = 0; m < 2; ++m)
#pragma unroll
        for (int sf = 0; sf < 4; ++sf) {
          f32x4 z = (f32x4){0.f, 0.f, 0.f, 0.f};
#pragma unroll
          for (int ck = 0; ck < 2; ++ck)
            z = __builtin_amdgcn_mfma_f32_16x16x32_bf16(qf[m][ck], kf[sf][ck], z, 0, 0, 0);
          sc_[m][sf] = z;
        }
    }
    // ---- build Vt = transpose of Vs (all threads) ----
    {
      const int d = tid & 63;
#pragma unroll
      for (int rep = 0; rep < 2; ++rep) {
        const int sc = (tid >> 6) + rep * 4;
        short8 t;
#pragma unroll
        for (int j = 0; j < 8; ++j) t[j] = (short)Vs[(sc * 8 + j) * 72 + d];
        *(short8*)(&Vt[sc * 512 + d * 8]) = t;
      }
    }
    __syncthreads();

    if (active) {
      // ---- online softmax ----
#pragma unroll
      for (int m = 0; m < 2; ++m) {
#pragma unroll
        for (int r = 0; r < 4; ++r) {
          const int lqr = qb * 128 + w * 32 + m * 16 + rg * 4 + r;
          float rowmax = -3e38f;
#pragma unroll
          for (int sf = 0; sf < 4; ++sf) {
            const int sg = kb * 64 + sf * 16 + fr;
            float v = sc_[m][sf][r];
            v = (sg <= lqr) ? v : -3e38f;
            sc_[m][sf][r] = v;
            rowmax = fmaxf(rowmax, v);
          }
#pragma unroll
          for (int msk = 1; msk < 16; msk <<= 1)
            rowmax = fmaxf(rowmax, __shfl_xor(rowmax, msk, 64));
          const float mold = m_run[m][r];
          const float mnew = fmaxf(mold, rowmax);
          const float scale = __expf(mold - mnew);
          m_run[m][r] = mnew;
          float psum = 0.f;
#pragma unroll
          for (int sf = 0; sf < 4; ++sf) {
            const float p = __expf(sc_[m][sf][r] - mnew);
            sc_[m][sf][r] = p;
            psum += p;
          }
#pragma unroll
          for (int msk = 1; msk < 16; msk <<= 1)
            psum += __shfl_xor(psum, msk, 64);
          l_run[m][r] = l_run[m][r] * scale + psum;
#pragma unroll
          for (int df = 0; df < 4; ++df) accO[m][df][r] *= scale;
        }
      }
      // ---- P -> LDS (bf16), per-wave region ----
#pragma unroll
      for (int m = 0; m < 2; ++m)
#pragma unroll
        for (int sf = 0; sf < 4; ++sf)
#pragma unroll
          for (int r = 0; r < 4; ++r)
            Pw[(m * 16 + rg * 4 + r) * 72 + sf * 16 + fr] = f2bf(sc_[m][sf][r]);
      // ---- PV ----
      short8 pf[2][2], vf[4][2];
#pragma unroll
      for (int m = 0; m < 2; ++m)
#pragma unroll
        for (int ck = 0; ck < 2; ++ck)
          pf[m][ck] = *(const short8*)(&Pw[(m * 16 + fr) * 72 + ck * 32 + rg * 8]);
#pragma unroll
      for (int df = 0; df < 4; ++df)
#pragma unroll
        for (int ck = 0; ck < 2; ++ck)
          vf[df][ck] = *(const short8*)(&Vt[(ck * 4 + rg) * 512 + (df * 16 + fr) * 8]);
#pragma unroll
      for (int m = 0; m < 2; ++m)
#pragma unroll
        for (int df = 0; df < 4; ++df)
#pragma unroll
          for (int ck = 0; ck < 2; ++ck)
            accO[m][df] = __builtin_amdgcn_mfma_f32_16x16x32_bf16(pf[m][ck], vf[df][ck], accO[m][df], 0, 0, 0);
    }
  }

  // ---- write O (bf16) ----
#pragma unroll
  for (int m = 0; m < 2; ++m)
#pragma unroll
    for (int df = 0; df < 4; ++df)
#pragma unroll
      for (int r = 0; r < 4; ++r) {
        const int lq = qb * 128 + w * 32 + m * 16 + rg * 4 + r;
        const int d = df * 16 + fr;
        Op[headoff + (size_t)lq * DM + d] = f2bf(accO[m][df][r] / l_run[m][r]);
      }
}

extern "C" void kernel_launch(void* const* d_in, const int* in_sizes, int n_in,
                              void* d_out, int out_size, void* d_ws, size_t ws_size,
                              hipStream_t stream) {
  (void)in_sizes; (void)n_in; (void)out_size; (void)ws_size;
  const float* queries = (const float*)d_in[0];
  const float* keys    = (const float*)d_in[1];
  const float* values  = (const float*)d_in[2];
  const float* Wq = (const float*)d_in[3];
  const float* bq = (const float*)d_in[4];
  const float* Wk = (const float*)d_in[5];
  const float* bk = (const float*)d_in[6];
  const float* Wv = (const float*)d_in[7];
  const float* bv = (const float*)d_in[8];
  const float* Wo = (const float*)d_in[9];
  const float* bo = (const float*)d_in[10];
  float* out = (float*)d_out;

  char* ws = (char*)d_ws;
  u16* Qb = (u16*)(ws);
  u16* Kb = (u16*)(ws + (size_t)8388608);
  u16* Vb = (u16*)(ws + (size_t)2 * 8388608);
  u16* Ob = (u16*)(ws + (size_t)3 * 8388608);
  float* cosT = (float*)(ws + (size_t)4 * 8388608);
  float* sinT = (float*)(ws + (size_t)4 * 8388608 + 262144);

  rope_table_kernel<<<dim3(SEQ * 32 / 256), 256, 0, stream>>>(cosT, sinT);
  dim3 gg(MROWS / 128, DM / 128);
  gemm_bt<1><<<gg, 256, 0, stream>>>(queries, nullptr, Wq, bq, Qb, nullptr, cosT, sinT, 0.125f);
  gemm_bt<1><<<gg, 256, 0, stream>>>(keys,    nullptr, Wk, bk, Kb, nullptr, cosT, sinT, 1.0f);
  gemm_bt<0><<<gg, 256, 0, stream>>>(values,  nullptr, Wv, bv, Vb, nullptr, nullptr, nullptr, 1.0f);
  flash_attn<<<dim3(SEQ / 128, NH, NB2), 256, 0, stream>>>(Qb, Kb, Vb, Ob);
  gemm_bt<2><<<gg, 256, 0, stream>>>(nullptr, Ob, Wo, bo, nullptr, out, nullptr, nullptr, 1.0f);
}

// Round 2
// 208.435 us; speedup vs baseline: 1.3005x; 1.3005x over previous
//
#include <hip/hip_runtime.h>
#include <math.h>

#define DM 1024
#define NH 16
#define HD 64
#define SEQ 2048
#define NB2 2
#define MROWS 4096   // NB2*SEQ

typedef unsigned short u16;
typedef __attribute__((ext_vector_type(8))) short short8;
typedef __attribute__((ext_vector_type(4))) float f32x4;

#define GLOAD16(g, l) __builtin_amdgcn_global_load_lds( \
    (const __attribute__((address_space(1))) void*)(g),  \
    (__attribute__((address_space(3))) void*)(l), 16, 0, 0)

static __device__ __forceinline__ u16 f2bf(float f) {
  union { float f; unsigned u; } v; v.f = f;
  unsigned r = v.u + 0x7fffu + ((v.u >> 16) & 1u);
  return (u16)(r >> 16);
}

static __device__ __forceinline__ short8 cvt8(float4 a, float4 b) {
  short8 s;
  s[0] = (short)f2bf(a.x); s[1] = (short)f2bf(a.y);
  s[2] = (short)f2bf(a.z); s[3] = (short)f2bf(a.w);
  s[4] = (short)f2bf(b.x); s[5] = (short)f2bf(b.y);
  s[6] = (short)f2bf(b.z); s[7] = (short)f2bf(b.w);
  return s;
}

// z=0..6: f32->bf16 conversion of {queries,keys,values,Wq,Wk,Wv,Wo}; z=7: rope table
__global__ void conv_all(
    const float* __restrict__ q, const float* __restrict__ k, const float* __restrict__ v,
    const float* __restrict__ wq, const float* __restrict__ wk,
    const float* __restrict__ wv, const float* __restrict__ wo,
    u16* __restrict__ xq, u16* __restrict__ xk, u16* __restrict__ xv,
    u16* __restrict__ wqb, u16* __restrict__ wkb, u16* __restrict__ wvb, u16* __restrict__ wob,
    float* __restrict__ cosT, float* __restrict__ sinT)
{
  const int z = blockIdx.z;
  const int idx = blockIdx.x * blockDim.x + threadIdx.x;
  if (z == 7) {
    if (idx >= SEQ * 32) return;
    int l = idx >> 5, i = idx & 31;
    float invf = expf(-(float)i * (9.210340371976184f / 32.0f)); // 10000^(-i/32)
    float ang = (float)l * invf;
    float s, c;
    sincosf(ang, &s, &c);
    cosT[idx] = c; sinT[idx] = s;
    return;
  }
  const float* src; u16* dst; int n;
  switch (z) {
    case 0: src = q;  dst = xq;  n = MROWS * DM; break;
    case 1: src = k;  dst = xk;  n = MROWS * DM; break;
    case 2: src = v;  dst = xv;  n = MROWS * DM; break;
    case 3: src = wq; dst = wqb; n = DM * DM; break;
    case 4: src = wk; dst = wkb; n = DM * DM; break;
    case 5: src = wv; dst = wvb; n = DM * DM; break;
    default: src = wo; dst = wob; n = DM * DM; break;
  }
  const int base = idx * 8;
  if (base >= n) return;
  float4 a = *(const float4*)(src + base);
  float4 b = *(const float4*)(src + base + 4);
  *(short8*)(dst + base) = cvt8(a, b);
}

// Shared GEMM body: C[128x128 tile] = A[128xK] * W[128xK]^T (+bias), K=1024.
// global_load_lds staging, LDS layout [kc(4)][row(128)][8].
template<int OUTF32>
__device__ __forceinline__ void gemm_body(
    u16* As, u16* Bs,
    const u16* __restrict__ A, const u16* __restrict__ W,
    const float* __restrict__ bias,
    u16* __restrict__ Cb, float* __restrict__ Cf,
    const float* __restrict__ cosT, const float* __restrict__ sinT,
    float qscale, int rope, int row0, int col0)
{
  const int tid = threadIdx.x;
  const int lane = tid & 63;
  const int w = tid >> 6;
  const int wr = w >> 1, wc = w & 1;
  const int fr = lane & 15, kg = lane >> 4;

  // staging: chunk c = w*128 + p*64 + lane ; kc = c>>7, row = c&127
  const int c0 = w * 128 + lane;
  const int c1 = c0 + 64;
  const u16* ga0 = A + (size_t)(row0 + (c0 & 127)) * DM + ((c0 >> 7) << 3);
  const u16* ga1 = A + (size_t)(row0 + (c1 & 127)) * DM + ((c1 >> 7) << 3);
  const u16* gb0 = W + (size_t)(col0 + (c0 & 127)) * DM + ((c0 >> 7) << 3);
  const u16* gb1 = W + (size_t)(col0 + (c1 & 127)) * DM + ((c1 >> 7) << 3);
  u16* la0 = As + (w * 128) * 8;
  u16* la1 = As + (w * 128 + 64) * 8;
  u16* lb0 = Bs + (w * 128) * 8;
  u16* lb1 = Bs + (w * 128 + 64) * 8;

  f32x4 acc[4][4];
#pragma unroll
  for (int m = 0; m < 4; ++m)
#pragma unroll
    for (int n = 0; n < 4; ++n) acc[m][n] = (f32x4){0.f, 0.f, 0.f, 0.f};

  const int KT = DM / 32;
  for (int kt = 0; kt < KT; ++kt) {
    const int ko = kt * 32;
    GLOAD16(ga0 + ko, la0);
    GLOAD16(ga1 + ko, la1);
    GLOAD16(gb0 + ko, lb0);
    GLOAD16(gb1 + ko, lb1);
    __syncthreads();   // drains vmcnt -> LDS staged
    short8 afr[4], bfr[4];
#pragma unroll
    for (int m = 0; m < 4; ++m)
      afr[m] = *(const short8*)(&As[kg * 1024 + (wr * 64 + m * 16 + fr) * 8]);
#pragma unroll
    for (int n = 0; n < 4; ++n)
      bfr[n] = *(const short8*)(&Bs[kg * 1024 + (wc * 64 + n * 16 + fr) * 8]);
#pragma unroll
    for (int m = 0; m < 4; ++m)
#pragma unroll
      for (int n = 0; n < 4; ++n)
        acc[m][n] = __builtin_amdgcn_mfma_f32_16x16x32_bf16(afr[m], bfr[n], acc[m][n], 0, 0, 0);
    __syncthreads();   // all reads done before next tile overwrites LDS
  }

  // epilogue: row = row0 + wr*64 + m*16 + kg*4 + r ; col = col0 + wc*64 + n*16 + fr
#pragma unroll
  for (int m = 0; m < 4; ++m) {
#pragma unroll
    for (int r = 0; r < 4; ++r) {
      const int rowg = row0 + wr * 64 + m * 16 + kg * 4 + r;
      if (OUTF32) {
#pragma unroll
        for (int n = 0; n < 4; ++n) {
          const int colg = col0 + wc * 64 + n * 16 + fr;
          Cf[(size_t)rowg * DM + colg] = acc[m][n][r] + bias[colg];
        }
      } else if (!rope) {
#pragma unroll
        for (int n = 0; n < 4; ++n) {
          const int colg = col0 + wc * 64 + n * 16 + fr;
          Cb[(size_t)rowg * DM + colg] = f2bf(acc[m][n][r] + bias[colg]);
        }
      } else {
        const int l = rowg & (SEQ - 1);
#pragma unroll
        for (int n = 0; n < 4; ++n) {
          const int colg = col0 + wc * 64 + n * 16 + fr;
          const int i = n * 16 + fr;      // position within head (0..63)
          const int fi = i & 31;          // freq index
          const float c = cosT[l * 32 + fi];
          const float s = sinT[l * 32 + fi];
          const float v = acc[m][n][r] + bias[colg];
          const float pv = acc[m][n ^ 2][r] + bias[col0 + wc * 64 + ((n ^ 2) * 16 + fr)];
          const float o = v * c + ((i < 32) ? -pv : pv) * s;
          Cb[(size_t)rowg * DM + colg] = f2bf(o * qscale);
        }
      }
    }
  }
}

// Fused Q/K/V projection: blockIdx.z selects input/weight/output. 768 blocks = 3/CU.
__global__ __launch_bounds__(256) void gemm_qkv(
    const u16* __restrict__ Xq, const u16* __restrict__ Xk, const u16* __restrict__ Xv,
    const u16* __restrict__ Wqb, const u16* __restrict__ Wkb, const u16* __restrict__ Wvb,
    const float* __restrict__ bq, const float* __restrict__ bk, const float* __restrict__ bv,
    u16* __restrict__ Qb, u16* __restrict__ Kb, u16* __restrict__ Vb,
    const float* __restrict__ cosT, const float* __restrict__ sinT)
{
  __shared__ __align__(16) u16 As[4096];
  __shared__ __align__(16) u16 Bs[4096];
  const int z = blockIdx.z;
  const u16* A = (z == 0) ? Xq : (z == 1) ? Xk : Xv;
  const u16* W = (z == 0) ? Wqb : (z == 1) ? Wkb : Wvb;
  const float* bias = (z == 0) ? bq : (z == 1) ? bk : bv;
  u16* C = (z == 0) ? Qb : (z == 1) ? Kb : Vb;
  const int rope = (z < 2) ? 1 : 0;
  const float qscale = (z == 0) ? 0.125f : 1.0f;
  gemm_body<0>(As, Bs, A, W, bias, C, nullptr, cosT, sinT, qscale, rope,
               blockIdx.x * 128, blockIdx.y * 128);
}

// Output projection: bf16 A (flash output), f32 out + bias.
__global__ __launch_bounds__(256) void gemm_o(
    const u16* __restrict__ Ob, const u16* __restrict__ Wob,
    const float* __restrict__ bo, float* __restrict__ out)
{
  __shared__ __align__(16) u16 As[4096];
  __shared__ __align__(16) u16 Bs[4096];
  gemm_body<1>(As, Bs, Ob, Wob, bo, nullptr, out, nullptr, nullptr, 1.0f, 0,
               blockIdx.x * 128, blockIdx.y * 128);
}

// Flash attention, causal, balanced: block processes q-tiles qbp and 15-qbp (17 k-tiles each pair half).
// 4 waves x 32 q-rows, KBLOCK=64, async-STAGE prefetch of next K/V tile.
__global__ __launch_bounds__(256) void flash_attn(
    const u16* __restrict__ Qp, const u16* __restrict__ Kp,
    const u16* __restrict__ Vp, u16* __restrict__ Op)
{
  __shared__ __align__(16) u16 Ks[4096];        // [dc(0..7)][s(0..63)][8]
  __shared__ __align__(16) u16 Vs[64 * 72];     // [s][72] padded row-major
  __shared__ __align__(16) u16 Vt[4096];        // [sc(0..7)][d(0..63)][8] : V^T mfma layout
  __shared__ __align__(16) u16 Ps[4 * 32 * 72]; // per-wave P tile [32][72]

  const int tid = threadIdx.x;
  const int lane = tid & 63;
  const int w = tid >> 6;
  const int fr = lane & 15, rg = lane >> 4;
  const int qbp = blockIdx.x;             // 0..7
  const int h = blockIdx.y, nb = blockIdx.z;

  const size_t headoff = (size_t)nb * SEQ * DM + (size_t)h * HD;
  const int ss = tid >> 3;    // 0..31
  const int sc8 = tid & 7;    // 16B chunk within row
  u16* Pw = &Ps[w * 2304];

  for (int pass = 0; pass < 2; ++pass) {
    const int qe = pass ? (15 - qbp) : qbp;
    const int KBend = 2 * qe + 2;
    const int rowmax_wave = qe * 128 + w * 32 + 31;

    short8 qf[2][2];
#pragma unroll
    for (int m = 0; m < 2; ++m)
#pragma unroll
      for (int ck = 0; ck < 2; ++ck)
        qf[m][ck] = *(const short8*)(Qp + headoff +
            (size_t)(qe * 128 + w * 32 + m * 16 + fr) * DM + ck * 32 + rg * 8);

    f32x4 accO[2][4];
    float m_run[2][4], l_run[2][4];
#pragma unroll
    for (int m = 0; m < 2; ++m) {
#pragma unroll
      for (int df = 0; df < 4; ++df) accO[m][df] = (f32x4){0.f, 0.f, 0.f, 0.f};
#pragma unroll
      for (int r = 0; r < 4; ++r) { m_run[m][r] = -3e38f; l_run[m][r] = 0.f; }
    }

    // prefetch kb=0 into registers
    short8 kpf[2], vpf[2];
#pragma unroll
    for (int rep = 0; rep < 2; ++rep) {
      const int s = ss + rep * 32;
      const size_t g = headoff + (size_t)s * DM + sc8 * 8;
      kpf[rep] = *(const short8*)(Kp + g);
      vpf[rep] = *(const short8*)(Vp + g);
    }

    for (int kb = 0; kb < KBend; ++kb) {
      // ---- write staged K/V regs to LDS ----
#pragma unroll
      for (int rep = 0; rep < 2; ++rep) {
        const int s = ss + rep * 32;
        *(short8*)(&Ks[sc8 * 512 + s * 8]) = kpf[rep];
        *(short8*)(&Vs[s * 72 + sc8 * 8]) = vpf[rep];
      }
      __syncthreads();
      // ---- issue next tile's global loads (latency hides under compute) ----
      if (kb + 1 < KBend) {
#pragma unroll
        for (int rep = 0; rep < 2; ++rep) {
          const int s = ss + rep * 32;
          const size_t g = headoff + (size_t)((kb + 1) * 64 + s) * DM + sc8 * 8;
          kpf[rep] = *(const short8*)(Kp + g);
          vpf[rep] = *(const short8*)(Vp + g);
        }
      }

      const bool active = (kb * 64) <= rowmax_wave;
      f32x4 sc_[2][4];
      if (active) {
        short8 kf[4][2];
#pragma unroll
        for (int sf = 0; sf < 4; ++sf)
#pragma unroll
          for (int ck = 0; ck < 2; ++ck)
            kf[sf][ck] = *(const short8*)(&Ks[(ck * 4 + rg) * 512 + (sf * 16 + fr) * 8]);
#pragma unroll
        for (int m = 0; m < 2; ++m)
#pragma unroll
          for (int sf = 0; sf < 4; ++sf) {
            f32x4 z = (f32x4){0.f, 0.f, 0.f, 0.f};
#pragma unroll
            for (int ck = 0; ck < 2; ++ck)
              z = __builtin_amdgcn_mfma_f32_16x16x32_bf16(qf[m][ck], kf[sf][ck], z, 0, 0, 0);
            sc_[m][sf] = z;
          }
      }
      // ---- build Vt = transpose of Vs (all threads) ----
      {
        const int d = tid & 63;
#pragma unroll
        for (int rep = 0; rep < 2; ++rep) {
          const int sc = (tid >> 6) + rep * 4;
          short8 t;
#pragma unroll
          for (int j = 0; j < 8; ++j) t[j] = (short)Vs[(sc * 8 + j) * 72 + d];
          *(short8*)(&Vt[sc * 512 + d * 8]) = t;
        }
      }
      __syncthreads();

      if (active) {
        // ---- online softmax ----
#pragma unroll
        for (int m = 0; m < 2; ++m) {
#pragma unroll
          for (int r = 0; r < 4; ++r) {
            const int lqr = qe * 128 + w * 32 + m * 16 + rg * 4 + r;
            float rowmax = -3e38f;
#pragma unroll
            for (int sf = 0; sf < 4; ++sf) {
              const int sg = kb * 64 + sf * 16 + fr;
              float v = sc_[m][sf][r];
              v = (sg <= lqr) ? v : -3e38f;
              sc_[m][sf][r] = v;
              rowmax = fmaxf(rowmax, v);
            }
#pragma unroll
            for (int msk = 1; msk < 16; msk <<= 1)
              rowmax = fmaxf(rowmax, __shfl_xor(rowmax, msk, 64));
            const float mold = m_run[m][r];
            const float mnew = fmaxf(mold, rowmax);
            const float scale = __expf(mold - mnew);
            m_run[m][r] = mnew;
            float psum = 0.f;
#pragma unroll
            for (int sf = 0; sf < 4; ++sf) {
              const float p = __expf(sc_[m][sf][r] - mnew);
              sc_[m][sf][r] = p;
              psum += p;
            }
#pragma unroll
            for (int msk = 1; msk < 16; msk <<= 1)
              psum += __shfl_xor(psum, msk, 64);
            l_run[m][r] = l_run[m][r] * scale + psum;
#pragma unroll
            for (int df = 0; df < 4; ++df) accO[m][df][r] *= scale;
          }
        }
        // ---- P -> LDS (bf16), per-wave region ----
#pragma unroll
        for (int m = 0; m < 2; ++m)
#pragma unroll
          for (int sf = 0; sf < 4; ++sf)
#pragma unroll
            for (int r = 0; r < 4; ++r)
              Pw[(m * 16 + rg * 4 + r) * 72 + sf * 16 + fr] = f2bf(sc_[m][sf][r]);
        // ---- PV ----
        short8 pf[2][2], vf[4][2];
#pragma unroll
        for (int m = 0; m < 2; ++m)
#pragma unroll
          for (int ck = 0; ck < 2; ++ck)
            pf[m][ck] = *(const short8*)(&Pw[(m * 16 + fr) * 72 + ck * 32 + rg * 8]);
#pragma unroll
        for (int df = 0; df < 4; ++df)
#pragma unroll
          for (int ck = 0; ck < 2; ++ck)
            vf[df][ck] = *(const short8*)(&Vt[(ck * 4 + rg) * 512 + (df * 16 + fr) * 8]);
#pragma unroll
        for (int m = 0; m < 2; ++m)
#pragma unroll
          for (int df = 0; df < 4; ++df)
#pragma unroll
            for (int ck = 0; ck < 2; ++ck)
              accO[m][df] = __builtin_amdgcn_mfma_f32_16x16x32_bf16(pf[m][ck], vf[df][ck], accO[m][df], 0, 0, 0);
      }
    }

    // ---- write O (bf16) for this q-tile ----
#pragma unroll
    for (int m = 0; m < 2; ++m)
#pragma unroll
      for (int df = 0; df < 4; ++df)
#pragma unroll
        for (int r = 0; r < 4; ++r) {
          const int lq = qe * 128 + w * 32 + m * 16 + rg * 4 + r;
          const int d = df * 16 + fr;
          Op[headoff + (size_t)lq * DM + d] = f2bf(accO[m][df][r] / l_run[m][r]);
        }
  }
}

extern "C" void kernel_launch(void* const* d_in, const int* in_sizes, int n_in,
                              void* d_out, int out_size, void* d_ws, size_t ws_size,
                              hipStream_t stream) {
  (void)in_sizes; (void)n_in; (void)out_size; (void)ws_size;
  const float* queries = (const float*)d_in[0];
  const float* keys    = (const float*)d_in[1];
  const float* values  = (const float*)d_in[2];
  const float* Wq = (const float*)d_in[3];
  const float* bq = (const float*)d_in[4];
  const float* Wk = (const float*)d_in[5];
  const float* bk = (const float*)d_in[6];
  const float* Wv = (const float*)d_in[7];
  const float* bv = (const float*)d_in[8];
  const float* Wo = (const float*)d_in[9];
  const float* bo = (const float*)d_in[10];
  float* out = (float*)d_out;

  char* ws = (char*)d_ws;
  const size_t MB = 1u << 20;
  u16* Qb  = (u16*)(ws);
  u16* Kb  = (u16*)(ws + 8 * MB);
  u16* Vb  = (u16*)(ws + 16 * MB);
  u16* Xq  = (u16*)(ws + 24 * MB);   // Ob aliases Xq (Xq dead after gemm_qkv)
  u16* Ob  = Xq;
  u16* Xk  = (u16*)(ws + 32 * MB);
  u16* Xv  = (u16*)(ws + 40 * MB);
  u16* Wqb = (u16*)(ws + 48 * MB);
  u16* Wkb = (u16*)(ws + 50 * MB);
  u16* Wvb = (u16*)(ws + 52 * MB);
  u16* Wob = (u16*)(ws + 54 * MB);
  float* cosT = (float*)(ws + 56 * MB);
  float* sinT = (float*)(ws + 56 * MB + 256 * 1024);

  conv_all<<<dim3(2048, 1, 8), 256, 0, stream>>>(
      queries, keys, values, Wq, Wk, Wv, Wo,
      Xq, Xk, Xv, Wqb, Wkb, Wvb, Wob, cosT, sinT);
  gemm_qkv<<<dim3(MROWS / 128, DM / 128, 3), 256, 0, stream>>>(
      Xq, Xk, Xv, Wqb, Wkb, Wvb, bq, bk, bv, Qb, Kb, Vb, cosT, sinT);
  flash_attn<<<dim3(SEQ / 256, NH, NB2), 256, 0, stream>>>(Qb, Kb, Vb, Ob);
  gemm_o<<<dim3(MROWS / 128, DM / 128), 256, 0, stream>>>(Ob, Wob, bo, out);
}

// Round 3
// 178.626 us; speedup vs baseline: 1.5176x; 1.1669x over previous
//
#include <hip/hip_runtime.h>
#include <math.h>

#define DM 1024
#define NH 16
#define HD 64
#define SEQ 2048
#define NB2 2
#define MROWS 4096   // NB2*SEQ

typedef unsigned short u16;
typedef __attribute__((ext_vector_type(8))) short short8;
typedef __attribute__((ext_vector_type(4))) float f32x4;

#define GLOAD16(g, l) __builtin_amdgcn_global_load_lds( \
    (const __attribute__((address_space(1))) void*)(g),  \
    (__attribute__((address_space(3))) void*)(l), 16, 0, 0)

static __device__ __forceinline__ u16 f2bf(float f) {
  union { float f; unsigned u; } v; v.f = f;
  unsigned r = v.u + 0x7fffu + ((v.u >> 16) & 1u);
  return (u16)(r >> 16);
}

static __device__ __forceinline__ short8 cvt8(float4 a, float4 b) {
  short8 s;
  s[0] = (short)f2bf(a.x); s[1] = (short)f2bf(a.y);
  s[2] = (short)f2bf(a.z); s[3] = (short)f2bf(a.w);
  s[4] = (short)f2bf(b.x); s[5] = (short)f2bf(b.y);
  s[6] = (short)f2bf(b.z); s[7] = (short)f2bf(b.w);
  return s;
}

// z=0..6: f32->bf16 conversion of {queries,keys,values,Wq,Wk,Wv,Wo}; z=7: rope table
__global__ void conv_all(
    const float* __restrict__ q, const float* __restrict__ k, const float* __restrict__ v,
    const float* __restrict__ wq, const float* __restrict__ wk,
    const float* __restrict__ wv, const float* __restrict__ wo,
    u16* __restrict__ xq, u16* __restrict__ xk, u16* __restrict__ xv,
    u16* __restrict__ wqb, u16* __restrict__ wkb, u16* __restrict__ wvb, u16* __restrict__ wob,
    float* __restrict__ cosT, float* __restrict__ sinT)
{
  const int z = blockIdx.z;
  const int idx = blockIdx.x * blockDim.x + threadIdx.x;
  if (z == 7) {
    if (idx >= SEQ * 32) return;
    int l = idx >> 5, i = idx & 31;
    float invf = expf(-(float)i * (9.210340371976184f / 32.0f)); // 10000^(-i/32)
    float ang = (float)l * invf;
    float s, c;
    sincosf(ang, &s, &c);
    cosT[idx] = c; sinT[idx] = s;
    return;
  }
  const float* src; u16* dst; int n;
  switch (z) {
    case 0: src = q;  dst = xq;  n = MROWS * DM; break;
    case 1: src = k;  dst = xk;  n = MROWS * DM; break;
    case 2: src = v;  dst = xv;  n = MROWS * DM; break;
    case 3: src = wq; dst = wqb; n = DM * DM; break;
    case 4: src = wk; dst = wkb; n = DM * DM; break;
    case 5: src = wv; dst = wvb; n = DM * DM; break;
    default: src = wo; dst = wob; n = DM * DM; break;
  }
  const int base = idx * 8;
  if (base >= n) return;
  float4 a = *(const float4*)(src + base);
  float4 b = *(const float4*)(src + base + 4);
  *(short8*)(dst + base) = cvt8(a, b);
}

// Shared GEMM body: C[128x128 tile] = A[128xK] * W[128xK]^T (+bias), K=1024.
// global_load_lds staging, LDS layout [kc(4)][row(128)][8].
template<int OUTF32>
__device__ __forceinline__ void gemm_body(
    u16* As, u16* Bs,
    const u16* __restrict__ A, const u16* __restrict__ W,
    const float* __restrict__ bias,
    u16* __restrict__ Cb, float* __restrict__ Cf,
    const float* __restrict__ cosT, const float* __restrict__ sinT,
    float qscale, int rope, int row0, int col0)
{
  const int tid = threadIdx.x;
  const int lane = tid & 63;
  const int w = tid >> 6;
  const int wr = w >> 1, wc = w & 1;
  const int fr = lane & 15, kg = lane >> 4;

  // staging: chunk c = w*128 + p*64 + lane ; kc = c>>7, row = c&127
  const int c0 = w * 128 + lane;
  const int c1 = c0 + 64;
  const u16* ga0 = A + (size_t)(row0 + (c0 & 127)) * DM + ((c0 >> 7) << 3);
  const u16* ga1 = A + (size_t)(row0 + (c1 & 127)) * DM + ((c1 >> 7) << 3);
  const u16* gb0 = W + (size_t)(col0 + (c0 & 127)) * DM + ((c0 >> 7) << 3);
  const u16* gb1 = W + (size_t)(col0 + (c1 & 127)) * DM + ((c1 >> 7) << 3);
  u16* la0 = As + (w * 128) * 8;
  u16* la1 = As + (w * 128 + 64) * 8;
  u16* lb0 = Bs + (w * 128) * 8;
  u16* lb1 = Bs + (w * 128 + 64) * 8;

  f32x4 acc[4][4];
#pragma unroll
  for (int m = 0; m < 4; ++m)
#pragma unroll
    for (int n = 0; n < 4; ++n) acc[m][n] = (f32x4){0.f, 0.f, 0.f, 0.f};

  const int KT = DM / 32;
  for (int kt = 0; kt < KT; ++kt) {
    const int ko = kt * 32;
    GLOAD16(ga0 + ko, la0);
    GLOAD16(ga1 + ko, la1);
    GLOAD16(gb0 + ko, lb0);
    GLOAD16(gb1 + ko, lb1);
    __syncthreads();   // drains vmcnt -> LDS staged
    short8 afr[4], bfr[4];
#pragma unroll
    for (int m = 0; m < 4; ++m)
      afr[m] = *(const short8*)(&As[kg * 1024 + (wr * 64 + m * 16 + fr) * 8]);
#pragma unroll
    for (int n = 0; n < 4; ++n)
      bfr[n] = *(const short8*)(&Bs[kg * 1024 + (wc * 64 + n * 16 + fr) * 8]);
#pragma unroll
    for (int m = 0; m < 4; ++m)
#pragma unroll
      for (int n = 0; n < 4; ++n)
        acc[m][n] = __builtin_amdgcn_mfma_f32_16x16x32_bf16(afr[m], bfr[n], acc[m][n], 0, 0, 0);
    __syncthreads();   // all reads done before next tile overwrites LDS
  }

  // epilogue: row = row0 + wr*64 + m*16 + kg*4 + r ; col = col0 + wc*64 + n*16 + fr
#pragma unroll
  for (int m = 0; m < 4; ++m) {
#pragma unroll
    for (int r = 0; r < 4; ++r) {
      const int rowg = row0 + wr * 64 + m * 16 + kg * 4 + r;
      if (OUTF32) {
#pragma unroll
        for (int n = 0; n < 4; ++n) {
          const int colg = col0 + wc * 64 + n * 16 + fr;
          Cf[(size_t)rowg * DM + colg] = acc[m][n][r] + bias[colg];
        }
      } else if (!rope) {
#pragma unroll
        for (int n = 0; n < 4; ++n) {
          const int colg = col0 + wc * 64 + n * 16 + fr;
          Cb[(size_t)rowg * DM + colg] = f2bf(acc[m][n][r] + bias[colg]);
        }
      } else {
        const int l = rowg & (SEQ - 1);
#pragma unroll
        for (int n = 0; n < 4; ++n) {
          const int colg = col0 + wc * 64 + n * 16 + fr;
          const int i = n * 16 + fr;      // position within head (0..63)
          const int fi = i & 31;          // freq index
          const float c = cosT[l * 32 + fi];
          const float s = sinT[l * 32 + fi];
          const float v = acc[m][n][r] + bias[colg];
          const float pv = acc[m][n ^ 2][r] + bias[col0 + wc * 64 + ((n ^ 2) * 16 + fr)];
          const float o = v * c + ((i < 32) ? -pv : pv) * s;
          Cb[(size_t)rowg * DM + colg] = f2bf(o * qscale);
        }
      }
    }
  }
}

// Fused Q/K/V projection: blockIdx.z selects input/weight/output. 768 blocks = 3/CU.
__global__ __launch_bounds__(256) void gemm_qkv(
    const u16* __restrict__ Xq, const u16* __restrict__ Xk, const u16* __restrict__ Xv,
    const u16* __restrict__ Wqb, const u16* __restrict__ Wkb, const u16* __restrict__ Wvb,
    const float* __restrict__ bq, const float* __restrict__ bk, const float* __restrict__ bv,
    u16* __restrict__ Qb, u16* __restrict__ Kb, u16* __restrict__ Vb,
    const float* __restrict__ cosT, const float* __restrict__ sinT)
{
  __shared__ __align__(16) u16 As[4096];
  __shared__ __align__(16) u16 Bs[4096];
  const int z = blockIdx.z;
  const u16* A = (z == 0) ? Xq : (z == 1) ? Xk : Xv;
  const u16* W = (z == 0) ? Wqb : (z == 1) ? Wkb : Wvb;
  const float* bias = (z == 0) ? bq : (z == 1) ? bk : bv;
  u16* C = (z == 0) ? Qb : (z == 1) ? Kb : Vb;
  const int rope = (z < 2) ? 1 : 0;
  const float qscale = (z == 0) ? 0.125f : 1.0f;
  gemm_body<0>(As, Bs, A, W, bias, C, nullptr, cosT, sinT, qscale, rope,
               blockIdx.x * 128, blockIdx.y * 128);
}

// Output projection: bf16 A (flash output), f32 out + bias.
__global__ __launch_bounds__(256) void gemm_o(
    const u16* __restrict__ Ob, const u16* __restrict__ Wob,
    const float* __restrict__ bo, float* __restrict__ out)
{
  __shared__ __align__(16) u16 As[4096];
  __shared__ __align__(16) u16 Bs[4096];
  gemm_body<1>(As, Bs, Ob, Wob, bo, nullptr, out, nullptr, nullptr, 1.0f, 0,
               blockIdx.x * 128, blockIdx.y * 128);
}

// Flash attention, causal, balanced pairing (qbp, 15-qbp), 8 waves x 16 q-rows,
// KBLOCK=64, async register prefetch of next K/V tile.
// P-tile LDS layout: stride 112 u16 + skew ((row>>2)&3)*16 u16  -> conflict-free
// scalar stores (banks r*24 + rg*8 + fr/2 cover all 32, 2 lanes each).
#define PSTR 112
__global__ __launch_bounds__(512) void flash_attn(
    const u16* __restrict__ Qp, const u16* __restrict__ Kp,
    const u16* __restrict__ Vp, u16* __restrict__ Op)
{
  __shared__ __align__(16) u16 Ks[4096];          // [dc(0..7)][s(0..63)][8]
  __shared__ __align__(16) u16 Vs[64 * 72];       // [s][72] padded row-major
  __shared__ __align__(16) u16 Vt[4096];          // [sc(0..7)][d(0..63)][8] : V^T mfma layout
  __shared__ __align__(16) u16 Ps[8 * 16 * PSTR]; // per-wave skewed P tile

  const int tid = threadIdx.x;
  const int lane = tid & 63;
  const int w = tid >> 6;                  // 0..7
  const int fr = lane & 15, rg = lane >> 4;
  const int qbp = blockIdx.x;              // 0..7
  const int h = blockIdx.y, nb = blockIdx.z;

  const size_t headoff = (size_t)nb * SEQ * DM + (size_t)h * HD;
  const int srow = tid >> 3;   // 0..63  (staging row)
  const int sch  = tid & 7;    // 16B chunk within row
  const int vsc = tid >> 6;    // 0..7   (transpose s-chunk)
  const int vd  = tid & 63;    //        (transpose d)
  u16* Pw = &Ps[w * 16 * PSTR];

  for (int pass = 0; pass < 2; ++pass) {
    const int qe = pass ? (15 - qbp) : qbp;
    const int KBend = 2 * qe + 2;
    const int qrow0 = qe * 128 + w * 16;
    const int rowmax_wave = qrow0 + 15;

    short8 qf[2];
#pragma unroll
    for (int ck = 0; ck < 2; ++ck)
      qf[ck] = *(const short8*)(Qp + headoff +
          (size_t)(qrow0 + fr) * DM + ck * 32 + rg * 8);

    f32x4 accO[4];
    float m_run[4], l_run[4];
#pragma unroll
    for (int df = 0; df < 4; ++df) accO[df] = (f32x4){0.f, 0.f, 0.f, 0.f};
#pragma unroll
    for (int r = 0; r < 4; ++r) { m_run[r] = -3e38f; l_run[r] = 0.f; }

    // prefetch kb=0 into registers (one 16B chunk of K and V per thread)
    short8 kpf, vpf;
    {
      const size_t g = headoff + (size_t)srow * DM + sch * 8;
      kpf = *(const short8*)(Kp + g);
      vpf = *(const short8*)(Vp + g);
    }

    for (int kb = 0; kb < KBend; ++kb) {
      // ---- write staged K/V regs to LDS ----
      *(short8*)(&Ks[sch * 512 + srow * 8]) = kpf;
      *(short8*)(&Vs[srow * 72 + sch * 8]) = vpf;
      __syncthreads();
      // ---- issue next tile's global loads (latency hides under compute) ----
      if (kb + 1 < KBend) {
        const size_t g = headoff + (size_t)((kb + 1) * 64 + srow) * DM + sch * 8;
        kpf = *(const short8*)(Kp + g);
        vpf = *(const short8*)(Vp + g);
      }

      const bool active = (kb * 64) <= rowmax_wave;
      f32x4 sc_[4];
      if (active) {
        short8 kf[4][2];
#pragma unroll
        for (int sf = 0; sf < 4; ++sf)
#pragma unroll
          for (int ck = 0; ck < 2; ++ck)
            kf[sf][ck] = *(const short8*)(&Ks[(ck * 4 + rg) * 512 + (sf * 16 + fr) * 8]);
#pragma unroll
        for (int sf = 0; sf < 4; ++sf) {
          f32x4 z = (f32x4){0.f, 0.f, 0.f, 0.f};
#pragma unroll
          for (int ck = 0; ck < 2; ++ck)
            z = __builtin_amdgcn_mfma_f32_16x16x32_bf16(qf[ck], kf[sf][ck], z, 0, 0, 0);
          sc_[sf] = z;
        }
      }
      // ---- build Vt = transpose of Vs (all threads, 1 row of 8 each) ----
      {
        short8 t;
#pragma unroll
        for (int j = 0; j < 8; ++j) t[j] = (short)Vs[(vsc * 8 + j) * 72 + vd];
        *(short8*)(&Vt[vsc * 512 + vd * 8]) = t;
      }
      __syncthreads();

      if (active) {
        // ---- online softmax (rows qrow0 + rg*4 + r) ----
#pragma unroll
        for (int r = 0; r < 4; ++r) {
          const int lqr = qrow0 + rg * 4 + r;
          float rowmax = -3e38f;
#pragma unroll
          for (int sf = 0; sf < 4; ++sf) {
            const int sg = kb * 64 + sf * 16 + fr;
            float v = sc_[sf][r];
            v = (sg <= lqr) ? v : -3e38f;
            sc_[sf][r] = v;
            rowmax = fmaxf(rowmax, v);
          }
#pragma unroll
          for (int msk = 1; msk < 16; msk <<= 1)
            rowmax = fmaxf(rowmax, __shfl_xor(rowmax, msk, 64));
          const float mold = m_run[r];
          const float mnew = fmaxf(mold, rowmax);
          const float scale = __expf(mold - mnew);
          m_run[r] = mnew;
          float psum = 0.f;
#pragma unroll
          for (int sf = 0; sf < 4; ++sf) {
            const float p = __expf(sc_[sf][r] - mnew);
            sc_[sf][r] = p;
            psum += p;
          }
#pragma unroll
          for (int msk = 1; msk < 16; msk <<= 1)
            psum += __shfl_xor(psum, msk, 64);
          l_run[r] = l_run[r] * scale + psum;
#pragma unroll
          for (int df = 0; df < 4; ++df) accO[df][r] *= scale;
        }
        // ---- P -> LDS (bf16), skewed per-wave region ----
#pragma unroll
        for (int sf = 0; sf < 4; ++sf)
#pragma unroll
          for (int r = 0; r < 4; ++r) {
            const int rowl = rg * 4 + r;
            Pw[rowl * PSTR + ((rowl >> 2) & 3) * 16 + sf * 16 + fr] = f2bf(sc_[sf][r]);
          }
        // ---- PV ----
        short8 pf[2], vf[4][2];
#pragma unroll
        for (int ck = 0; ck < 2; ++ck)
          pf[ck] = *(const short8*)(&Pw[fr * PSTR + ((fr >> 2) & 3) * 16 + ck * 32 + rg * 8]);
#pragma unroll
        for (int df = 0; df < 4; ++df)
#pragma unroll
          for (int ck = 0; ck < 2; ++ck)
            vf[df][ck] = *(const short8*)(&Vt[(ck * 4 + rg) * 512 + (df * 16 + fr) * 8]);
#pragma unroll
        for (int df = 0; df < 4; ++df)
#pragma unroll
          for (int ck = 0; ck < 2; ++ck)
            accO[df] = __builtin_amdgcn_mfma_f32_16x16x32_bf16(pf[ck], vf[df][ck], accO[df], 0, 0, 0);
      }
    }

    // ---- write O (bf16) for this q-tile ----
#pragma unroll
    for (int df = 0; df < 4; ++df)
#pragma unroll
      for (int r = 0; r < 4; ++r) {
        const int lq = qrow0 + rg * 4 + r;
        const int d = df * 16 + fr;
        Op[headoff + (size_t)lq * DM + d] = f2bf(accO[df][r] / l_run[r]);
      }
  }
}

extern "C" void kernel_launch(void* const* d_in, const int* in_sizes, int n_in,
                              void* d_out, int out_size, void* d_ws, size_t ws_size,
                              hipStream_t stream) {
  (void)in_sizes; (void)n_in; (void)out_size; (void)ws_size;
  const float* queries = (const float*)d_in[0];
  const float* keys    = (const float*)d_in[1];
  const float* values  = (const float*)d_in[2];
  const float* Wq = (const float*)d_in[3];
  const float* bq = (const float*)d_in[4];
  const float* Wk = (const float*)d_in[5];
  const float* bk = (const float*)d_in[6];
  const float* Wv = (const float*)d_in[7];
  const float* bv = (const float*)d_in[8];
  const float* Wo = (const float*)d_in[9];
  const float* bo = (const float*)d_in[10];
  float* out = (float*)d_out;

  char* ws = (char*)d_ws;
  const size_t MB = 1u << 20;
  u16* Qb  = (u16*)(ws);
  u16* Kb  = (u16*)(ws + 8 * MB);
  u16* Vb  = (u16*)(ws + 16 * MB);
  u16* Xq  = (u16*)(ws + 24 * MB);   // Ob aliases Xq (Xq dead after gemm_qkv)
  u16* Ob  = Xq;
  u16* Xk  = (u16*)(ws + 32 * MB);
  u16* Xv  = (u16*)(ws + 40 * MB);
  u16* Wqb = (u16*)(ws + 48 * MB);
  u16* Wkb = (u16*)(ws + 50 * MB);
  u16* Wvb = (u16*)(ws + 52 * MB);
  u16* Wob = (u16*)(ws + 54 * MB);
  float* cosT = (float*)(ws + 56 * MB);
  float* sinT = (float*)(ws + 56 * MB + 256 * 1024);

  conv_all<<<dim3(2048, 1, 8), 256, 0, stream>>>(
      queries, keys, values, Wq, Wk, Wv, Wo,
      Xq, Xk, Xv, Wqb, Wkb, Wvb, Wob, cosT, sinT);
  gemm_qkv<<<dim3(MROWS / 128, DM / 128, 3), 256, 0, stream>>>(
      Xq, Xk, Xv, Wqb, Wkb, Wvb, bq, bk, bv, Qb, Kb, Vb, cosT, sinT);
  flash_attn<<<dim3(SEQ / 256, NH, NB2), 512, 0, stream>>>(Qb, Kb, Vb, Ob);
  gemm_o<<<dim3(MROWS / 128, DM / 128), 256, 0, stream>>>(Ob, Wob, bo, out);
}

// Round 4
// 164.567 us; speedup vs baseline: 1.6472x; 1.0854x over previous
//
#include <hip/hip_runtime.h>
#include <math.h>

#define DM 1024
#define NH 16
#define HD 64
#define SEQ 2048
#define NB2 2
#define MROWS 4096   // NB2*SEQ

typedef unsigned short u16;
typedef __attribute__((ext_vector_type(8))) short short8;
typedef __attribute__((ext_vector_type(4))) float f32x4;
typedef __attribute__((ext_vector_type(2))) unsigned int u32x2;

#define GLOAD16(g, l) __builtin_amdgcn_global_load_lds( \
    (const __attribute__((address_space(1))) void*)(g),  \
    (__attribute__((address_space(3))) void*)(l), 16, 0, 0)

static __device__ __forceinline__ u16 f2bf(float f) {
  union { float f; unsigned u; } v; v.f = f;
  unsigned r = v.u + 0x7fffu + ((v.u >> 16) & 1u);
  return (u16)(r >> 16);
}

static __device__ __forceinline__ short8 cvt8(float4 a, float4 b) {
  short8 s;
  s[0] = (short)f2bf(a.x); s[1] = (short)f2bf(a.y);
  s[2] = (short)f2bf(a.z); s[3] = (short)f2bf(a.w);
  s[4] = (short)f2bf(b.x); s[5] = (short)f2bf(b.y);
  s[6] = (short)f2bf(b.z); s[7] = (short)f2bf(b.w);
  return s;
}

// z=0..6: f32->bf16 conversion of {queries,keys,values,Wq,Wk,Wv,Wo}; z=7: rope table
__global__ void conv_all(
    const float* __restrict__ q, const float* __restrict__ k, const float* __restrict__ v,
    const float* __restrict__ wq, const float* __restrict__ wk,
    const float* __restrict__ wv, const float* __restrict__ wo,
    u16* __restrict__ xq, u16* __restrict__ xk, u16* __restrict__ xv,
    u16* __restrict__ wqb, u16* __restrict__ wkb, u16* __restrict__ wvb, u16* __restrict__ wob,
    float* __restrict__ cosT, float* __restrict__ sinT)
{
  const int z = blockIdx.z;
  const int idx = blockIdx.x * blockDim.x + threadIdx.x;
  if (z == 7) {
    if (idx >= SEQ * 32) return;
    int l = idx >> 5, i = idx & 31;
    float invf = expf(-(float)i * (9.210340371976184f / 32.0f)); // 10000^(-i/32)
    float ang = (float)l * invf;
    float s, c;
    sincosf(ang, &s, &c);
    cosT[idx] = c; sinT[idx] = s;
    return;
  }
  const float* src; u16* dst; int n;
  switch (z) {
    case 0: src = q;  dst = xq;  n = MROWS * DM; break;
    case 1: src = k;  dst = xk;  n = MROWS * DM; break;
    case 2: src = v;  dst = xv;  n = MROWS * DM; break;
    case 3: src = wq; dst = wqb; n = DM * DM; break;
    case 4: src = wk; dst = wkb; n = DM * DM; break;
    case 5: src = wv; dst = wvb; n = DM * DM; break;
    default: src = wo; dst = wob; n = DM * DM; break;
  }
  const int base = idx * 8;
  if (base >= n) return;
  float4 a = *(const float4*)(src + base);
  float4 b = *(const float4*)(src + base + 4);
  *(short8*)(dst + base) = cvt8(a, b);
}

// Shared GEMM body: C[128x128 tile] = A[128xK] * W[128xK]^T (+bias), K=1024.
// EPI 0: bf16 out + RoPE (*qscale). EPI 1: f32 out. EPI 2: transposed bf16 out to VT.
#define VSTR 136   // u16 stride of transpose-bounce buffer (272B, 16B-aligned)
template<int EPI>
__device__ __forceinline__ void gemm_body(
    u16* SH,
    const u16* __restrict__ A, const u16* __restrict__ W,
    const float* __restrict__ bias,
    u16* __restrict__ Cb, float* __restrict__ Cf, u16* __restrict__ VT,
    const float* __restrict__ cosT, const float* __restrict__ sinT,
    float qscale, int row0, int col0)
{
  u16* As = SH;
  u16* Bs = SH + 4096;
  const int tid = threadIdx.x;
  const int lane = tid & 63;
  const int w = tid >> 6;
  const int wr = w >> 1, wc = w & 1;
  const int fr = lane & 15, kg = lane >> 4;

  // staging: chunk c = w*128 + p*64 + lane ; kc = c>>7, row = c&127
  const int c0 = w * 128 + lane;
  const int c1 = c0 + 64;
  const u16* ga0 = A + (size_t)(row0 + (c0 & 127)) * DM + ((c0 >> 7) << 3);
  const u16* ga1 = A + (size_t)(row0 + (c1 & 127)) * DM + ((c1 >> 7) << 3);
  const u16* gb0 = W + (size_t)(col0 + (c0 & 127)) * DM + ((c0 >> 7) << 3);
  const u16* gb1 = W + (size_t)(col0 + (c1 & 127)) * DM + ((c1 >> 7) << 3);
  u16* la0 = As + (w * 128) * 8;
  u16* la1 = As + (w * 128 + 64) * 8;
  u16* lb0 = Bs + (w * 128) * 8;
  u16* lb1 = Bs + (w * 128 + 64) * 8;

  f32x4 acc[4][4];
#pragma unroll
  for (int m = 0; m < 4; ++m)
#pragma unroll
    for (int n = 0; n < 4; ++n) acc[m][n] = (f32x4){0.f, 0.f, 0.f, 0.f};

  const int KT = DM / 32;
  for (int kt = 0; kt < KT; ++kt) {
    const int ko = kt * 32;
    GLOAD16(ga0 + ko, la0);
    GLOAD16(ga1 + ko, la1);
    GLOAD16(gb0 + ko, lb0);
    GLOAD16(gb1 + ko, lb1);
    __syncthreads();   // drains vmcnt -> LDS staged
    short8 afr[4], bfr[4];
#pragma unroll
    for (int m = 0; m < 4; ++m)
      afr[m] = *(const short8*)(&As[kg * 1024 + (wr * 64 + m * 16 + fr) * 8]);
#pragma unroll
    for (int n = 0; n < 4; ++n)
      bfr[n] = *(const short8*)(&Bs[kg * 1024 + (wc * 64 + n * 16 + fr) * 8]);
#pragma unroll
    for (int m = 0; m < 4; ++m)
#pragma unroll
      for (int n = 0; n < 4; ++n)
        acc[m][n] = __builtin_amdgcn_mfma_f32_16x16x32_bf16(afr[m], bfr[n], acc[m][n], 0, 0, 0);
    __syncthreads();   // all reads done before next tile overwrites LDS
  }

  if (EPI == 2) {
    // transposed write: VT[(nb*NH + e/64)*64 + e%64][row0%2048 + s] = C[s][e]
    const int nb = row0 >> 11;
    const int sbase = row0 & (SEQ - 1);
#pragma unroll
    for (int p = 0; p < 2; ++p) {
      if (wc == p) {
#pragma unroll
        for (int n = 0; n < 4; ++n) {
          const int dcol = n * 16 + fr;
          const float bv = bias[col0 + p * 64 + dcol];
#pragma unroll
          for (int m = 0; m < 4; ++m)
#pragma unroll
            for (int r = 0; r < 4; ++r)
              SH[dcol * VSTR + wr * 64 + m * 16 + kg * 4 + r] = f2bf(acc[m][n][r] + bv);
        }
      }
      __syncthreads();
      {
        const int dcol = tid >> 2, sq = tid & 3;
        const int e = col0 + p * 64 + dcol;
        u16* dst = VT + ((size_t)(nb * NH + (e >> 6)) * HD + (e & 63)) * SEQ + sbase + sq * 32;
#pragma unroll
        for (int i = 0; i < 4; ++i)
          *(short8*)(dst + i * 8) = *(const short8*)(&SH[dcol * VSTR + sq * 32 + i * 8]);
      }
      __syncthreads();
    }
    return;
  }

  // epilogue: row = row0 + wr*64 + m*16 + kg*4 + r ; col = col0 + wc*64 + n*16 + fr
#pragma unroll
  for (int m = 0; m < 4; ++m) {
#pragma unroll
    for (int r = 0; r < 4; ++r) {
      const int rowg = row0 + wr * 64 + m * 16 + kg * 4 + r;
      if (EPI == 1) {
#pragma unroll
        for (int n = 0; n < 4; ++n) {
          const int colg = col0 + wc * 64 + n * 16 + fr;
          Cf[(size_t)rowg * DM + colg] = acc[m][n][r] + bias[colg];
        }
      } else {
        const int l = rowg & (SEQ - 1);
#pragma unroll
        for (int n = 0; n < 4; ++n) {
          const int colg = col0 + wc * 64 + n * 16 + fr;
          const int i = n * 16 + fr;      // position within head (0..63)
          const int fi = i & 31;          // freq index
          const float c = cosT[l * 32 + fi];
          const float s = sinT[l * 32 + fi];
          const float v = acc[m][n][r] + bias[colg];
          const float pv = acc[m][n ^ 2][r] + bias[col0 + wc * 64 + ((n ^ 2) * 16 + fr)];
          const float o = v * c + ((i < 32) ? -pv : pv) * s;
          Cb[(size_t)rowg * DM + colg] = f2bf(o * qscale);
        }
      }
    }
  }
}

// Fused Q/K/V projection. z=0: Q (rope, scaled); z=1: K (rope); z=2: V -> VT (transposed).
__global__ __launch_bounds__(256) void gemm_qkv(
    const u16* __restrict__ Xq, const u16* __restrict__ Xk, const u16* __restrict__ Xv,
    const u16* __restrict__ Wqb, const u16* __restrict__ Wkb, const u16* __restrict__ Wvb,
    const float* __restrict__ bq, const float* __restrict__ bk, const float* __restrict__ bv,
    u16* __restrict__ Qb, u16* __restrict__ Kb, u16* __restrict__ VT,
    const float* __restrict__ cosT, const float* __restrict__ sinT)
{
  __shared__ __align__(16) u16 SH[64 * VSTR];
  const int z = blockIdx.z;
  const int row0 = blockIdx.x * 128, col0 = blockIdx.y * 128;
  if (z == 2) {
    gemm_body<2>(SH, Xv, Wvb, bv, nullptr, nullptr, VT, nullptr, nullptr, 1.0f, row0, col0);
  } else if (z == 0) {
    gemm_body<0>(SH, Xq, Wqb, bq, Qb, nullptr, nullptr, cosT, sinT, 0.125f, row0, col0);
  } else {
    gemm_body<0>(SH, Xk, Wkb, bk, Kb, nullptr, nullptr, cosT, sinT, 1.0f, row0, col0);
  }
}

// Output projection: bf16 A (flash output), f32 out + bias.
__global__ __launch_bounds__(256) void gemm_o(
    const u16* __restrict__ Ob, const u16* __restrict__ Wob,
    const float* __restrict__ bo, float* __restrict__ out)
{
  __shared__ __align__(16) u16 SH[64 * VSTR];
  gemm_body<1>(SH, Ob, Wob, bo, nullptr, out, nullptr, nullptr, nullptr, 1.0f,
               blockIdx.x * 128, blockIdx.y * 128);
}

// Flash attention, causal, balanced pairing (qbp, 15-qbp), 8 waves x 16 q-rows.
// Swapped QK^T (mfma(K,Q)) -> lane-local softmax; K/V^T staged via XOR-swizzled
// conflict-free LDS; P redistributed through a per-wave LDS strip (no barrier).
__global__ __launch_bounds__(512) void flash_attn(
    const u16* __restrict__ Qp, const u16* __restrict__ Kp,
    const u16* __restrict__ VT, u16* __restrict__ Op)
{
  __shared__ __align__(16) u16 Ks[4096];   // swizzled: chunk c = dc*64 + (s^dc), 16B chunks
  __shared__ __align__(16) u16 Vt[4096];   // swizzled: chunk c = sc*64 + (d^sc)
  __shared__ __align__(16) u16 Pl[9216];   // per-wave P strip: [fr][36 dwords], 144B row stride

  const int tid = threadIdx.x;
  const int lane = tid & 63;
  const int w = tid >> 6;                  // 0..7
  const int fr = lane & 15, rg = lane >> 4;
  const int qbp = blockIdx.x;              // 0..7
  const int h = blockIdx.y, nb = blockIdx.z;

  const size_t headoff = (size_t)nb * SEQ * DM + (size_t)h * HD;      // Q, K, O
  const size_t vthead = (size_t)(nb * NH + h) * HD * SEQ;             // V^T
  const int srow = tid >> 3;   // 0..63 (staging row: s for K, d for V^T)
  const int sch  = tid & 7;    // 16B chunk within row
  u16* Pw = &Pl[w * 1152];

  for (int pass = 0; pass < 2; ++pass) {
    const int qe = pass ? (15 - qbp) : qbp;
    const int KBend = 2 * qe + 2;
    const int qrow0 = qe * 128 + w * 16;
    const int qg = qrow0 + fr;             // this lane's softmax q-row

    short8 qf[2];
#pragma unroll
    for (int ck = 0; ck < 2; ++ck)
      qf[ck] = *(const short8*)(Qp + headoff + (size_t)(qrow0 + fr) * DM + ck * 32 + rg * 8);

    f32x4 accO[4];
#pragma unroll
    for (int df = 0; df < 4; ++df) accO[df] = (f32x4){0.f, 0.f, 0.f, 0.f};
    float m_run = -3e38f, l_run = 0.f;

    // prefetch kb=0 (one 16B chunk of K and V^T per thread)
    short8 kpf = *(const short8*)(Kp + headoff + (size_t)srow * DM + sch * 8);
    short8 vpf = *(const short8*)(VT + vthead + (size_t)srow * SEQ + sch * 8);

    for (int kb = 0; kb < KBend; ++kb) {
      // ---- staged regs -> swizzled LDS (conflict-free) ----
      *(short8*)(&Ks[(sch * 64 + (srow ^ sch)) * 8]) = kpf;
      *(short8*)(&Vt[(sch * 64 + (srow ^ sch)) * 8]) = vpf;
      __syncthreads();
      // ---- issue next tile's global loads (hide under compute) ----
      if (kb + 1 < KBend) {
        kpf = *(const short8*)(Kp + headoff + (size_t)((kb + 1) * 64 + srow) * DM + sch * 8);
        vpf = *(const short8*)(VT + vthead + (size_t)srow * SEQ + (kb + 1) * 64 + sch * 8);
      }

      const bool active = (kb * 64) <= (qrow0 + 15);
      if (active) {
        // ---- QK^T swapped: D[s][q], s = kb*64 + sf*16 + rg*4 + r, q = qg ----
        short8 kf[4][2];
#pragma unroll
        for (int sf = 0; sf < 4; ++sf)
#pragma unroll
          for (int ck = 0; ck < 2; ++ck) {
            const int dc = ck * 4 + rg;
            kf[sf][ck] = *(const short8*)(&Ks[(dc * 64 + ((sf * 16 + fr) ^ dc)) * 8]);
          }
        f32x4 sc_[4];
#pragma unroll
        for (int sf = 0; sf < 4; ++sf) {
          f32x4 z = (f32x4){0.f, 0.f, 0.f, 0.f};
#pragma unroll
          for (int ck = 0; ck < 2; ++ck)
            z = __builtin_amdgcn_mfma_f32_16x16x32_bf16(kf[sf][ck], qf[ck], z, 0, 0, 0);
          sc_[sf] = z;
        }
        // ---- mask + in-register softmax (all 16 values are row qg) ----
        float rowmax = -3e38f;
#pragma unroll
        for (int sf = 0; sf < 4; ++sf)
#pragma unroll
          for (int r = 0; r < 4; ++r) {
            const int sg = kb * 64 + sf * 16 + rg * 4 + r;
            float v = sc_[sf][r];
            v = (sg <= qg) ? v : -3e38f;
            sc_[sf][r] = v;
            rowmax = fmaxf(rowmax, v);
          }
        rowmax = fmaxf(rowmax, __shfl_xor(rowmax, 16, 64));
        rowmax = fmaxf(rowmax, __shfl_xor(rowmax, 32, 64));
        const float mnew = fmaxf(m_run, rowmax);
        const float scl = __expf(m_run - mnew);
        m_run = mnew;
        float psum = 0.f;
#pragma unroll
        for (int sf = 0; sf < 4; ++sf)
#pragma unroll
          for (int r = 0; r < 4; ++r) {
            const float p = __expf(sc_[sf][r] - mnew);
            sc_[sf][r] = p;
            psum += p;
          }
        psum += __shfl_xor(psum, 16, 64);
        psum += __shfl_xor(psum, 32, 64);
        l_run = l_run * scl + psum;
        // ---- rescale accO (its rows are q = qrow0 + rg*4 + r) ----
        const float s0 = __shfl(scl, rg * 4 + 0, 64);
        const float s1 = __shfl(scl, rg * 4 + 1, 64);
        const float s2 = __shfl(scl, rg * 4 + 2, 64);
        const float s3 = __shfl(scl, rg * 4 + 3, 64);
#pragma unroll
        for (int df = 0; df < 4; ++df) {
          accO[df][0] *= s0; accO[df][1] *= s1;
          accO[df][2] *= s2; accO[df][3] *= s3;
        }
        // ---- pack P to bf16 pairs, redistribute via per-wave LDS strip ----
#pragma unroll
        for (int sf = 0; sf < 4; ++sf) {
          u32x2 pv;
          pv[0] = (unsigned)f2bf(sc_[sf][0]) | ((unsigned)f2bf(sc_[sf][1]) << 16);
          pv[1] = (unsigned)f2bf(sc_[sf][2]) | ((unsigned)f2bf(sc_[sf][3]) << 16);
          *(u32x2*)(&Pw[fr * 72 + (sf * 8 + rg * 2) * 2]) = pv;
        }
        short8 pa[2];
#pragma unroll
        for (int ck = 0; ck < 2; ++ck)
          pa[ck] = *(const short8*)(&Pw[fr * 72 + (ck * 16 + rg * 4) * 2]);
        // ---- PV: A = P[q][s], B = V[s][d] from swizzled Vt ----
#pragma unroll
        for (int df = 0; df < 4; ++df)
#pragma unroll
          for (int ck = 0; ck < 2; ++ck) {
            const int sc = ck * 4 + rg;
            const short8 vf = *(const short8*)(&Vt[(sc * 64 + ((df * 16 + fr) ^ sc)) * 8]);
            accO[df] = __builtin_amdgcn_mfma_f32_16x16x32_bf16(pa[ck], vf, accO[df], 0, 0, 0);
          }
      }
      __syncthreads();   // compute reads done before next staging overwrites
    }

    // ---- write O (bf16); accO row q = qrow0 + rg*4 + r ----
    const float l0 = __shfl(l_run, rg * 4 + 0, 64);
    const float l1 = __shfl(l_run, rg * 4 + 1, 64);
    const float l2 = __shfl(l_run, rg * 4 + 2, 64);
    const float l3 = __shfl(l_run, rg * 4 + 3, 64);
#pragma unroll
    for (int df = 0; df < 4; ++df) {
      const int d = df * 16 + fr;
      Op[headoff + (size_t)(qrow0 + rg * 4 + 0) * DM + d] = f2bf(accO[df][0] / l0);
      Op[headoff + (size_t)(qrow0 + rg * 4 + 1) * DM + d] = f2bf(accO[df][1] / l1);
      Op[headoff + (size_t)(qrow0 + rg * 4 + 2) * DM + d] = f2bf(accO[df][2] / l2);
      Op[headoff + (size_t)(qrow0 + rg * 4 + 3) * DM + d] = f2bf(accO[df][3] / l3);
    }
  }
}

extern "C" void kernel_launch(void* const* d_in, const int* in_sizes, int n_in,
                              void* d_out, int out_size, void* d_ws, size_t ws_size,
                              hipStream_t stream) {
  (void)in_sizes; (void)n_in; (void)out_size; (void)ws_size;
  const float* queries = (const float*)d_in[0];
  const float* keys    = (const float*)d_in[1];
  const float* values  = (const float*)d_in[2];
  const float* Wq = (const float*)d_in[3];
  const float* bq = (const float*)d_in[4];
  const float* Wk = (const float*)d_in[5];
  const float* bk = (const float*)d_in[6];
  const float* Wv = (const float*)d_in[7];
  const float* bv = (const float*)d_in[8];
  const float* Wo = (const float*)d_in[9];
  const float* bo = (const float*)d_in[10];
  float* out = (float*)d_out;

  char* ws = (char*)d_ws;
  const size_t MB = 1u << 20;
  u16* Qb  = (u16*)(ws);
  u16* Kb  = (u16*)(ws + 8 * MB);
  u16* VTg = (u16*)(ws + 16 * MB);
  u16* Xq  = (u16*)(ws + 24 * MB);   // Ob aliases Xq (Xq dead after gemm_qkv)
  u16* Ob  = Xq;
  u16* Xk  = (u16*)(ws + 32 * MB);
  u16* Xv  = (u16*)(ws + 40 * MB);
  u16* Wqb = (u16*)(ws + 48 * MB);
  u16* Wkb = (u16*)(ws + 50 * MB);
  u16* Wvb = (u16*)(ws + 52 * MB);
  u16* Wob = (u16*)(ws + 54 * MB);
  float* cosT = (float*)(ws + 56 * MB);
  float* sinT = (float*)(ws + 56 * MB + 256 * 1024);

  conv_all<<<dim3(2048, 1, 8), 256, 0, stream>>>(
      queries, keys, values, Wq, Wk, Wv, Wo,
      Xq, Xk, Xv, Wqb, Wkb, Wvb, Wob, cosT, sinT);
  gemm_qkv<<<dim3(MROWS / 128, DM / 128, 3), 256, 0, stream>>>(
      Xq, Xk, Xv, Wqb, Wkb, Wvb, bq, bk, bv, Qb, Kb, VTg, cosT, sinT);
  flash_attn<<<dim3(SEQ / 256, NH, NB2), 512, 0, stream>>>(Qb, Kb, VTg, Ob);
  gemm_o<<<dim3(MROWS / 128, DM / 128), 256, 0, stream>>>(Ob, Wob, bo, out);
}

// Round 5
// 157.998 us; speedup vs baseline: 1.7157x; 1.0416x over previous
//
#include <hip/hip_runtime.h>
#include <math.h>

#define DM 1024
#define NH 16
#define HD 64
#define SEQ 2048
#define NB2 2
#define MROWS 4096   // NB2*SEQ

typedef unsigned short u16;
typedef __attribute__((ext_vector_type(8))) short short8;
typedef __attribute__((ext_vector_type(4))) float f32x4;
typedef __attribute__((ext_vector_type(2))) unsigned int u32x2;

#define GLOAD16(g, l) __builtin_amdgcn_global_load_lds( \
    (const __attribute__((address_space(1))) void*)(g),  \
    (__attribute__((address_space(3))) void*)(l), 16, 0, 0)

static __device__ __forceinline__ u16 f2bf(float f) {
  union { float f; unsigned u; } v; v.f = f;
  unsigned r = v.u + 0x7fffu + ((v.u >> 16) & 1u);
  return (u16)(r >> 16);
}

static __device__ __forceinline__ short8 cvt8(float4 a, float4 b) {
  short8 s;
  s[0] = (short)f2bf(a.x); s[1] = (short)f2bf(a.y);
  s[2] = (short)f2bf(a.z); s[3] = (short)f2bf(a.w);
  s[4] = (short)f2bf(b.x); s[5] = (short)f2bf(b.y);
  s[6] = (short)f2bf(b.z); s[7] = (short)f2bf(b.w);
  return s;
}

// z=0..6: f32->bf16 conversion of {queries,keys,values,Wq,Wk,Wv,Wo}; z=7: rope table
__global__ void conv_all(
    const float* __restrict__ q, const float* __restrict__ k, const float* __restrict__ v,
    const float* __restrict__ wq, const float* __restrict__ wk,
    const float* __restrict__ wv, const float* __restrict__ wo,
    u16* __restrict__ xq, u16* __restrict__ xk, u16* __restrict__ xv,
    u16* __restrict__ wqb, u16* __restrict__ wkb, u16* __restrict__ wvb, u16* __restrict__ wob,
    float* __restrict__ cosT, float* __restrict__ sinT)
{
  const int z = blockIdx.z;
  const int idx = blockIdx.x * blockDim.x + threadIdx.x;
  if (z == 7) {
    if (idx >= SEQ * 32) return;
    int l = idx >> 5, i = idx & 31;
    float invf = expf(-(float)i * (9.210340371976184f / 32.0f)); // 10000^(-i/32)
    float ang = (float)l * invf;
    float s, c;
    sincosf(ang, &s, &c);
    cosT[idx] = c; sinT[idx] = s;
    return;
  }
  const float* src; u16* dst; int n;
  switch (z) {
    case 0: src = q;  dst = xq;  n = MROWS * DM; break;
    case 1: src = k;  dst = xk;  n = MROWS * DM; break;
    case 2: src = v;  dst = xv;  n = MROWS * DM; break;
    case 3: src = wq; dst = wqb; n = DM * DM; break;
    case 4: src = wk; dst = wkb; n = DM * DM; break;
    case 5: src = wv; dst = wvb; n = DM * DM; break;
    default: src = wo; dst = wob; n = DM * DM; break;
  }
  const int base = idx * 8;
  if (base >= n) return;
  float4 a = *(const float4*)(src + base);
  float4 b = *(const float4*)(src + base + 4);
  *(short8*)(dst + base) = cvt8(a, b);
}

// Shared GEMM body: C[128x128 tile] = A[128xK] * W[128xK]^T (+bias), K=1024.
// Double-buffered LDS, stage(t+1) issued before compute(t), ONE barrier per
// K-step (its implicit vmcnt(0) waits loads that overlapped the compute).
// EPI 0: bf16 out + RoPE (*qscale). EPI 1: f32 out. EPI 2: transposed bf16 out to VT.
#define VSTR 136   // u16 stride of transpose-bounce buffer (272B, 16B-aligned)
template<int EPI>
__device__ __forceinline__ void gemm_body(
    u16* SH,
    const u16* __restrict__ A, const u16* __restrict__ W,
    const float* __restrict__ bias,
    u16* __restrict__ Cb, float* __restrict__ Cf, u16* __restrict__ VT,
    const float* __restrict__ cosT, const float* __restrict__ sinT,
    float qscale, int row0, int col0)
{
  u16* As0 = SH;          u16* Bs0 = SH + 4096;
  u16* As1 = SH + 8192;   u16* Bs1 = SH + 12288;
  const int tid = threadIdx.x;
  const int lane = tid & 63;
  const int w = tid >> 6;
  const int wr = w >> 1, wc = w & 1;
  const int fr = lane & 15, kg = lane >> 4;

  // staging: chunk c = w*128 + p*64 + lane ; kc = c>>7, row = c&127
  const int c0 = w * 128 + lane;
  const int c1 = c0 + 64;
  const u16* ga0 = A + (size_t)(row0 + (c0 & 127)) * DM + ((c0 >> 7) << 3);
  const u16* ga1 = A + (size_t)(row0 + (c1 & 127)) * DM + ((c1 >> 7) << 3);
  const u16* gb0 = W + (size_t)(col0 + (c0 & 127)) * DM + ((c0 >> 7) << 3);
  const u16* gb1 = W + (size_t)(col0 + (c1 & 127)) * DM + ((c1 >> 7) << 3);
  const int lo0 = (w * 128) * 8;        // wave-uniform LDS offsets
  const int lo1 = (w * 128 + 64) * 8;

  f32x4 acc[4][4];
#pragma unroll
  for (int m = 0; m < 4; ++m)
#pragma unroll
    for (int n = 0; n < 4; ++n) acc[m][n] = (f32x4){0.f, 0.f, 0.f, 0.f};

  // prologue: stage kt=0 into buf0
  GLOAD16(ga0, As0 + lo0);
  GLOAD16(ga1, As0 + lo1);
  GLOAD16(gb0, Bs0 + lo0);
  GLOAD16(gb1, Bs0 + lo1);

  const int KT = DM / 32;
  for (int kt = 0; kt < KT; ++kt) {
    u16* Ar = (kt & 1) ? As1 : As0;
    u16* Br = (kt & 1) ? Bs1 : Bs0;
    u16* Aw = (kt & 1) ? As0 : As1;
    u16* Bw = (kt & 1) ? Bs0 : Bs1;
    __syncthreads();   // drains stage(kt); prev-iter reads of Aw/Bw done
    if (kt + 1 < KT) {
      const int ko = (kt + 1) * 32;
      GLOAD16(ga0 + ko, Aw + lo0);
      GLOAD16(ga1 + ko, Aw + lo1);
      GLOAD16(gb0 + ko, Bw + lo0);
      GLOAD16(gb1 + ko, Bw + lo1);
    }
    short8 afr[4], bfr[4];
#pragma unroll
    for (int m = 0; m < 4; ++m)
      afr[m] = *(const short8*)(&Ar[kg * 1024 + (wr * 64 + m * 16 + fr) * 8]);
#pragma unroll
    for (int n = 0; n < 4; ++n)
      bfr[n] = *(const short8*)(&Br[kg * 1024 + (wc * 64 + n * 16 + fr) * 8]);
#pragma unroll
    for (int m = 0; m < 4; ++m)
#pragma unroll
      for (int n = 0; n < 4; ++n)
        acc[m][n] = __builtin_amdgcn_mfma_f32_16x16x32_bf16(afr[m], bfr[n], acc[m][n], 0, 0, 0);
  }

  if (EPI == 2) {
    __syncthreads();   // last-iter LDS reads done before SH reuse
    // transposed write: VT[(nb*NH + e/64)*64 + e%64][row0%2048 + s] = C[s][e]
    const int nb = row0 >> 11;
    const int sbase = row0 & (SEQ - 1);
#pragma unroll
    for (int p = 0; p < 2; ++p) {
      if (wc == p) {
#pragma unroll
        for (int n = 0; n < 4; ++n) {
          const int dcol = n * 16 + fr;
          const float bv = bias[col0 + p * 64 + dcol];
#pragma unroll
          for (int m = 0; m < 4; ++m)
#pragma unroll
            for (int r = 0; r < 4; ++r)
              SH[dcol * VSTR + wr * 64 + m * 16 + kg * 4 + r] = f2bf(acc[m][n][r] + bv);
        }
      }
      __syncthreads();
      {
        const int dcol = tid >> 2, sq = tid & 3;
        const int e = col0 + p * 64 + dcol;
        u16* dst = VT + ((size_t)(nb * NH + (e >> 6)) * HD + (e & 63)) * SEQ + sbase + sq * 32;
#pragma unroll
        for (int i = 0; i < 4; ++i)
          *(short8*)(dst + i * 8) = *(const short8*)(&SH[dcol * VSTR + sq * 32 + i * 8]);
      }
      __syncthreads();
    }
    return;
  }

  // epilogue: row = row0 + wr*64 + m*16 + kg*4 + r ; col = col0 + wc*64 + n*16 + fr
#pragma unroll
  for (int m = 0; m < 4; ++m) {
#pragma unroll
    for (int r = 0; r < 4; ++r) {
      const int rowg = row0 + wr * 64 + m * 16 + kg * 4 + r;
      if (EPI == 1) {
#pragma unroll
        for (int n = 0; n < 4; ++n) {
          const int colg = col0 + wc * 64 + n * 16 + fr;
          Cf[(size_t)rowg * DM + colg] = acc[m][n][r] + bias[colg];
        }
      } else {
        const int l = rowg & (SEQ - 1);
#pragma unroll
        for (int n = 0; n < 4; ++n) {
          const int colg = col0 + wc * 64 + n * 16 + fr;
          const int i = n * 16 + fr;      // position within head (0..63)
          const int fi = i & 31;          // freq index
          const float c = cosT[l * 32 + fi];
          const float s = sinT[l * 32 + fi];
          const float v = acc[m][n][r] + bias[colg];
          const float pv = acc[m][n ^ 2][r] + bias[col0 + wc * 64 + ((n ^ 2) * 16 + fr)];
          const float o = v * c + ((i < 32) ? -pv : pv) * s;
          Cb[(size_t)rowg * DM + colg] = f2bf(o * qscale);
        }
      }
    }
  }
}

// Fused Q/K/V projection. z=0: Q (rope, scaled); z=1: K (rope); z=2: V -> VT (transposed).
__global__ __launch_bounds__(256) void gemm_qkv(
    const u16* __restrict__ Xq, const u16* __restrict__ Xk, const u16* __restrict__ Xv,
    const u16* __restrict__ Wqb, const u16* __restrict__ Wkb, const u16* __restrict__ Wvb,
    const float* __restrict__ bq, const float* __restrict__ bk, const float* __restrict__ bv,
    u16* __restrict__ Qb, u16* __restrict__ Kb, u16* __restrict__ VT,
    const float* __restrict__ cosT, const float* __restrict__ sinT)
{
  __shared__ __align__(16) u16 SH[16384];   // 32 KB: dbuf As/Bs; reused as transpose bounce
  const int z = blockIdx.z;
  const int row0 = blockIdx.x * 128, col0 = blockIdx.y * 128;
  if (z == 2) {
    gemm_body<2>(SH, Xv, Wvb, bv, nullptr, nullptr, VT, nullptr, nullptr, 1.0f, row0, col0);
  } else if (z == 0) {
    gemm_body<0>(SH, Xq, Wqb, bq, Qb, nullptr, nullptr, cosT, sinT, 0.125f, row0, col0);
  } else {
    gemm_body<0>(SH, Xk, Wkb, bk, Kb, nullptr, nullptr, cosT, sinT, 1.0f, row0, col0);
  }
}

// Output projection: bf16 A (flash output), f32 out + bias.
__global__ __launch_bounds__(256) void gemm_o(
    const u16* __restrict__ Ob, const u16* __restrict__ Wob,
    const float* __restrict__ bo, float* __restrict__ out)
{
  __shared__ __align__(16) u16 SH[16384];
  gemm_body<1>(SH, Ob, Wob, bo, nullptr, out, nullptr, nullptr, nullptr, 1.0f,
               blockIdx.x * 128, blockIdx.y * 128);
}

// Flash attention, causal, balanced pairing (qbp, 15-qbp), 8 waves x 16 q-rows.
// Swapped QK^T (mfma(K,Q)) -> lane-local softmax; K/V^T staged via XOR-swizzled
// conflict-free LDS; P redistributed through a per-wave LDS strip (no barrier).
__global__ __launch_bounds__(512) void flash_attn(
    const u16* __restrict__ Qp, const u16* __restrict__ Kp,
    const u16* __restrict__ VT, u16* __restrict__ Op)
{
  __shared__ __align__(16) u16 Ks[4096];   // swizzled: chunk c = dc*64 + (s^dc), 16B chunks
  __shared__ __align__(16) u16 Vt[4096];   // swizzled: chunk c = sc*64 + (d^sc)
  __shared__ __align__(16) u16 Pl[9216];   // per-wave P strip: [fr][36 dwords], 144B row stride

  const int tid = threadIdx.x;
  const int lane = tid & 63;
  const int w = tid >> 6;                  // 0..7
  const int fr = lane & 15, rg = lane >> 4;
  const int qbp = blockIdx.x;              // 0..7
  const int h = blockIdx.y, nb = blockIdx.z;

  const size_t headoff = (size_t)nb * SEQ * DM + (size_t)h * HD;      // Q, K, O
  const size_t vthead = (size_t)(nb * NH + h) * HD * SEQ;             // V^T
  const int srow = tid >> 3;   // 0..63 (staging row: s for K, d for V^T)
  const int sch  = tid & 7;    // 16B chunk within row
  u16* Pw = &Pl[w * 1152];

  for (int pass = 0; pass < 2; ++pass) {
    const int qe = pass ? (15 - qbp) : qbp;
    const int KBend = 2 * qe + 2;
    const int qrow0 = qe * 128 + w * 16;
    const int qg = qrow0 + fr;             // this lane's softmax q-row

    short8 qf[2];
#pragma unroll
    for (int ck = 0; ck < 2; ++ck)
      qf[ck] = *(const short8*)(Qp + headoff + (size_t)(qrow0 + fr) * DM + ck * 32 + rg * 8);

    f32x4 accO[4];
#pragma unroll
    for (int df = 0; df < 4; ++df) accO[df] = (f32x4){0.f, 0.f, 0.f, 0.f};
    float m_run = -3e38f, l_run = 0.f;

    // prefetch kb=0 (one 16B chunk of K and V^T per thread)
    short8 kpf = *(const short8*)(Kp + headoff + (size_t)srow * DM + sch * 8);
    short8 vpf = *(const short8*)(VT + vthead + (size_t)srow * SEQ + sch * 8);

    for (int kb = 0; kb < KBend; ++kb) {
      // ---- staged regs -> swizzled LDS (conflict-free) ----
      *(short8*)(&Ks[(sch * 64 + (srow ^ sch)) * 8]) = kpf;
      *(short8*)(&Vt[(sch * 64 + (srow ^ sch)) * 8]) = vpf;
      __syncthreads();
      // ---- issue next tile's global loads (hide under compute) ----
      if (kb + 1 < KBend) {
        kpf = *(const short8*)(Kp + headoff + (size_t)((kb + 1) * 64 + srow) * DM + sch * 8);
        vpf = *(const short8*)(VT + vthead + (size_t)srow * SEQ + (kb + 1) * 64 + sch * 8);
      }

      const bool active = (kb * 64) <= (qrow0 + 15);
      if (active) {
        // ---- QK^T swapped: D[s][q], s = kb*64 + sf*16 + rg*4 + r, q = qg ----
        short8 kf[4][2];
#pragma unroll
        for (int sf = 0; sf < 4; ++sf)
#pragma unroll
          for (int ck = 0; ck < 2; ++ck) {
            const int dc = ck * 4 + rg;
            kf[sf][ck] = *(const short8*)(&Ks[(dc * 64 + ((sf * 16 + fr) ^ dc)) * 8]);
          }
        f32x4 sc_[4];
#pragma unroll
        for (int sf = 0; sf < 4; ++sf) {
          f32x4 z = (f32x4){0.f, 0.f, 0.f, 0.f};
#pragma unroll
          for (int ck = 0; ck < 2; ++ck)
            z = __builtin_amdgcn_mfma_f32_16x16x32_bf16(kf[sf][ck], qf[ck], z, 0, 0, 0);
          sc_[sf] = z;
        }
        // ---- mask + in-register softmax (all 16 values are row qg) ----
        float rowmax = -3e38f;
#pragma unroll
        for (int sf = 0; sf < 4; ++sf)
#pragma unroll
          for (int r = 0; r < 4; ++r) {
            const int sg = kb * 64 + sf * 16 + rg * 4 + r;
            float v = sc_[sf][r];
            v = (sg <= qg) ? v : -3e38f;
            sc_[sf][r] = v;
            rowmax = fmaxf(rowmax, v);
          }
        rowmax = fmaxf(rowmax, __shfl_xor(rowmax, 16, 64));
        rowmax = fmaxf(rowmax, __shfl_xor(rowmax, 32, 64));
        const float mnew = fmaxf(m_run, rowmax);
        const float scl = __expf(m_run - mnew);
        m_run = mnew;
        float psum = 0.f;
#pragma unroll
        for (int sf = 0; sf < 4; ++sf)
#pragma unroll
          for (int r = 0; r < 4; ++r) {
            const float p = __expf(sc_[sf][r] - mnew);
            sc_[sf][r] = p;
            psum += p;
          }
        psum += __shfl_xor(psum, 16, 64);
        psum += __shfl_xor(psum, 32, 64);
        l_run = l_run * scl + psum;
        // ---- rescale accO (its rows are q = qrow0 + rg*4 + r) ----
        const float s0 = __shfl(scl, rg * 4 + 0, 64);
        const float s1 = __shfl(scl, rg * 4 + 1, 64);
        const float s2 = __shfl(scl, rg * 4 + 2, 64);
        const float s3 = __shfl(scl, rg * 4 + 3, 64);
#pragma unroll
        for (int df = 0; df < 4; ++df) {
          accO[df][0] *= s0; accO[df][1] *= s1;
          accO[df][2] *= s2; accO[df][3] *= s3;
        }
        // ---- pack P to bf16 pairs, redistribute via per-wave LDS strip ----
#pragma unroll
        for (int sf = 0; sf < 4; ++sf) {
          u32x2 pv;
          pv[0] = (unsigned)f2bf(sc_[sf][0]) | ((unsigned)f2bf(sc_[sf][1]) << 16);
          pv[1] = (unsigned)f2bf(sc_[sf][2]) | ((unsigned)f2bf(sc_[sf][3]) << 16);
          *(u32x2*)(&Pw[fr * 72 + (sf * 8 + rg * 2) * 2]) = pv;
        }
        short8 pa[2];
#pragma unroll
        for (int ck = 0; ck < 2; ++ck)
          pa[ck] = *(const short8*)(&Pw[fr * 72 + (ck * 16 + rg * 4) * 2]);
        // ---- PV: A = P[q][s], B = V[s][d] from swizzled Vt ----
#pragma unroll
        for (int df = 0; df < 4; ++df)
#pragma unroll
          for (int ck = 0; ck < 2; ++ck) {
            const int sc = ck * 4 + rg;
            const short8 vf = *(const short8*)(&Vt[(sc * 64 + ((df * 16 + fr) ^ sc)) * 8]);
            accO[df] = __builtin_amdgcn_mfma_f32_16x16x32_bf16(pa[ck], vf, accO[df], 0, 0, 0);
          }
      }
      __syncthreads();   // compute reads done before next staging overwrites
    }

    // ---- write O (bf16); accO row q = qrow0 + rg*4 + r ----
    const float l0 = __shfl(l_run, rg * 4 + 0, 64);
    const float l1 = __shfl(l_run, rg * 4 + 1, 64);
    const float l2 = __shfl(l_run, rg * 4 + 2, 64);
    const float l3 = __shfl(l_run, rg * 4 + 3, 64);
#pragma unroll
    for (int df = 0; df < 4; ++df) {
      const int d = df * 16 + fr;
      Op[headoff + (size_t)(qrow0 + rg * 4 + 0) * DM + d] = f2bf(accO[df][0] / l0);
      Op[headoff + (size_t)(qrow0 + rg * 4 + 1) * DM + d] = f2bf(accO[df][1] / l1);
      Op[headoff + (size_t)(qrow0 + rg * 4 + 2) * DM + d] = f2bf(accO[df][2] / l2);
      Op[headoff + (size_t)(qrow0 + rg * 4 + 3) * DM + d] = f2bf(accO[df][3] / l3);
    }
  }
}

extern "C" void kernel_launch(void* const* d_in, const int* in_sizes, int n_in,
                              void* d_out, int out_size, void* d_ws, size_t ws_size,
                              hipStream_t stream) {
  (void)in_sizes; (void)n_in; (void)out_size; (void)ws_size;
  const float* queries = (const float*)d_in[0];
  const float* keys    = (const float*)d_in[1];
  const float* values  = (const float*)d_in[2];
  const float* Wq = (const float*)d_in[3];
  const float* bq = (const float*)d_in[4];
  const float* Wk = (const float*)d_in[5];
  const float* bk = (const float*)d_in[6];
  const float* Wv = (const float*)d_in[7];
  const float* bv = (const float*)d_in[8];
  const float* Wo = (const float*)d_in[9];
  const float* bo = (const float*)d_in[10];
  float* out = (float*)d_out;

  char* ws = (char*)d_ws;
  const size_t MB = 1u << 20;
  u16* Qb  = (u16*)(ws);
  u16* Kb  = (u16*)(ws + 8 * MB);
  u16* VTg = (u16*)(ws + 16 * MB);
  u16* Xq  = (u16*)(ws + 24 * MB);   // Ob aliases Xq (Xq dead after gemm_qkv)
  u16* Ob  = Xq;
  u16* Xk  = (u16*)(ws + 32 * MB);
  u16* Xv  = (u16*)(ws + 40 * MB);
  u16* Wqb = (u16*)(ws + 48 * MB);
  u16* Wkb = (u16*)(ws + 50 * MB);
  u16* Wvb = (u16*)(ws + 52 * MB);
  u16* Wob = (u16*)(ws + 54 * MB);
  float* cosT = (float*)(ws + 56 * MB);
  float* sinT = (float*)(ws + 56 * MB + 256 * 1024);

  conv_all<<<dim3(2048, 1, 8), 256, 0, stream>>>(
      queries, keys, values, Wq, Wk, Wv, Wo,
      Xq, Xk, Xv, Wqb, Wkb, Wvb, Wob, cosT, sinT);
  gemm_qkv<<<dim3(MROWS / 128, DM / 128, 3), 256, 0, stream>>>(
      Xq, Xk, Xv, Wqb, Wkb, Wvb, bq, bk, bv, Qb, Kb, VTg, cosT, sinT);
  flash_attn<<<dim3(SEQ / 256, NH, NB2), 512, 0, stream>>>(Qb, Kb, VTg, Ob);
  gemm_o<<<dim3(MROWS / 128, DM / 128), 256, 0, stream>>>(Ob, Wob, bo, out);
}

// Round 6
// 141.319 us; speedup vs baseline: 1.9182x; 1.1180x over previous
//
#include <hip/hip_runtime.h>
#include <math.h>

#define DM 1024
#define NH 16
#define HD 64
#define SEQ 2048
#define NB2 2
#define MROWS 4096   // NB2*SEQ

typedef unsigned short u16;
typedef __attribute__((ext_vector_type(8))) short short8;
typedef __attribute__((ext_vector_type(4))) float f32x4;
typedef __attribute__((ext_vector_type(2))) unsigned int u32x2;

#define GLOAD16(g, l) __builtin_amdgcn_global_load_lds( \
    (const __attribute__((address_space(1))) void*)(g),  \
    (__attribute__((address_space(3))) void*)(l), 16, 0, 0)

static __device__ __forceinline__ u16 f2bf(float f) {
  union { float f; unsigned u; } v; v.f = f;
  unsigned r = v.u + 0x7fffu + ((v.u >> 16) & 1u);
  return (u16)(r >> 16);
}

static __device__ __forceinline__ short8 cvt8(float4 a, float4 b) {
  short8 s;
  s[0] = (short)f2bf(a.x); s[1] = (short)f2bf(a.y);
  s[2] = (short)f2bf(a.z); s[3] = (short)f2bf(a.w);
  s[4] = (short)f2bf(b.x); s[5] = (short)f2bf(b.y);
  s[6] = (short)f2bf(b.z); s[7] = (short)f2bf(b.w);
  return s;
}

// z=0..6: f32->bf16 conversion of {queries,keys,values,Wq,Wk,Wv,Wo}; z=7: rope table
__global__ void conv_all(
    const float* __restrict__ q, const float* __restrict__ k, const float* __restrict__ v,
    const float* __restrict__ wq, const float* __restrict__ wk,
    const float* __restrict__ wv, const float* __restrict__ wo,
    u16* __restrict__ xq, u16* __restrict__ xk, u16* __restrict__ xv,
    u16* __restrict__ wqb, u16* __restrict__ wkb, u16* __restrict__ wvb, u16* __restrict__ wob,
    float* __restrict__ cosT, float* __restrict__ sinT)
{
  const int z = blockIdx.z;
  const int idx = blockIdx.x * blockDim.x + threadIdx.x;
  if (z == 7) {
    if (idx >= SEQ * 32) return;
    int l = idx >> 5, i = idx & 31;
    float invf = expf(-(float)i * (9.210340371976184f / 32.0f)); // 10000^(-i/32)
    float ang = (float)l * invf;
    float s, c;
    sincosf(ang, &s, &c);
    cosT[idx] = c; sinT[idx] = s;
    return;
  }
  const float* src; u16* dst; int n;
  switch (z) {
    case 0: src = q;  dst = xq;  n = MROWS * DM; break;
    case 1: src = k;  dst = xk;  n = MROWS * DM; break;
    case 2: src = v;  dst = xv;  n = MROWS * DM; break;
    case 3: src = wq; dst = wqb; n = DM * DM; break;
    case 4: src = wk; dst = wkb; n = DM * DM; break;
    case 5: src = wv; dst = wvb; n = DM * DM; break;
    default: src = wo; dst = wob; n = DM * DM; break;
  }
  const int base = idx * 8;
  if (base >= n) return;
  float4 a = *(const float4*)(src + base);
  float4 b = *(const float4*)(src + base + 4);
  *(short8*)(dst + base) = cvt8(a, b);
}

// Shared GEMM body: C[128x128 tile] = A[128xK] * W[128xK]^T (+bias), K=1024.
// Depth-2 prefetch over 3 LDS buffers with counted vmcnt (never 0 in main loop):
//   iter t: s_waitcnt vmcnt(4) [tile t landed, t+1 in flight] -> s_barrier ->
//           issue tile t+2 -> compute tile t.
// EPI 0: bf16 out + RoPE (*qscale). EPI 1: f32 out. EPI 2: transposed bf16 out to VT.
#define VSTR 136   // u16 stride of transpose-bounce buffer (272B, 16B-aligned)
template<int EPI>
__device__ __forceinline__ void gemm_body(
    u16* SH,
    const u16* __restrict__ A, const u16* __restrict__ W,
    const float* __restrict__ bias,
    u16* __restrict__ Cb, float* __restrict__ Cf, u16* __restrict__ VT,
    const float* __restrict__ cosT, const float* __restrict__ sinT,
    float qscale, int row0, int col0)
{
  const int tid = threadIdx.x;
  const int lane = tid & 63;
  const int w = tid >> 6;
  const int wr = w >> 1, wc = w & 1;
  const int fr = lane & 15, kg = lane >> 4;

  // staging: chunk c = w*128 + p*64 + lane ; kc = c>>7, row = c&127
  const int c0 = w * 128 + lane;
  const int c1 = c0 + 64;
  const u16* ga0 = A + (size_t)(row0 + (c0 & 127)) * DM + ((c0 >> 7) << 3);
  const u16* ga1 = A + (size_t)(row0 + (c1 & 127)) * DM + ((c1 >> 7) << 3);
  const u16* gb0 = W + (size_t)(col0 + (c0 & 127)) * DM + ((c0 >> 7) << 3);
  const u16* gb1 = W + (size_t)(col0 + (c1 & 127)) * DM + ((c1 >> 7) << 3);
  const int lo0 = (w * 128) * 8;        // wave-uniform LDS offsets
  const int lo1 = (w * 128 + 64) * 8;
  const int aoffL = kg * 1024 + (wr * 64 + fr) * 8;          // + m*128
  const int boffL = 4096 + kg * 1024 + (wc * 64 + fr) * 8;   // + n*128

  u16* B0 = SH;
  u16* B1 = SH + 8192;
  u16* B2 = SH + 16384;

  f32x4 acc[4][4];
#pragma unroll
  for (int m = 0; m < 4; ++m)
#pragma unroll
    for (int n = 0; n < 4; ++n) acc[m][n] = (f32x4){0.f, 0.f, 0.f, 0.f};

  auto issue = [&](int t, u16* buf) {
    const int ko = t * 32;
    GLOAD16(ga0 + ko, buf + lo0);
    GLOAD16(ga1 + ko, buf + lo1);
    GLOAD16(gb0 + ko, buf + 4096 + lo0);
    GLOAD16(gb1 + ko, buf + 4096 + lo1);
  };
  auto compute = [&](const u16* buf) {
    short8 afr[4], bfr[4];
#pragma unroll
    for (int m = 0; m < 4; ++m)
      afr[m] = *(const short8*)(&buf[aoffL + m * 128]);
#pragma unroll
    for (int n = 0; n < 4; ++n)
      bfr[n] = *(const short8*)(&buf[boffL + n * 128]);
#pragma unroll
    for (int m = 0; m < 4; ++m)
#pragma unroll
      for (int n = 0; n < 4; ++n)
        acc[m][n] = __builtin_amdgcn_mfma_f32_16x16x32_bf16(afr[m], bfr[n], acc[m][n], 0, 0, 0);
  };

  // prologue: depth-2 prefetch
  issue(0, B0);
  issue(1, B1);

#define STEP4(t, bufR, bufW) do {                                   \
    asm volatile("s_waitcnt vmcnt(4)" ::: "memory");                \
    __builtin_amdgcn_sched_barrier(0);                              \
    __builtin_amdgcn_s_barrier();                                   \
    __builtin_amdgcn_sched_barrier(0);                              \
    if ((t) + 2 < 32) issue((t) + 2, bufW);                         \
    compute(bufR);                                                  \
  } while (0)
#define STEP0(t, bufR) do {                                         \
    asm volatile("s_waitcnt vmcnt(0)" ::: "memory");                \
    __builtin_amdgcn_sched_barrier(0);                              \
    __builtin_amdgcn_s_barrier();                                   \
    __builtin_amdgcn_sched_barrier(0);                              \
    compute(bufR);                                                  \
  } while (0)

  for (int t = 0; t < 30; t += 3) {
    STEP4(t,     B0, B2);
    STEP4(t + 1, B1, B0);
    STEP4(t + 2, B2, B1);
  }
  STEP4(30, B0, B2);   // t+2 = 32 -> no issue; waits tile 30 (31 still in flight)
  STEP0(31, B1);       // drain: tile 31 landed
#undef STEP4
#undef STEP0

  if (EPI == 2) {
    __syncthreads();   // last-iter LDS reads done before SH reuse
    // transposed write: VT[(nb*NH + e/64)*64 + e%64][row0%2048 + s] = C[s][e]
    const int nb = row0 >> 11;
    const int sbase = row0 & (SEQ - 1);
#pragma unroll
    for (int p = 0; p < 2; ++p) {
      if (wc == p) {
#pragma unroll
        for (int n = 0; n < 4; ++n) {
          const int dcol = n * 16 + fr;
          const float bv = bias[col0 + p * 64 + dcol];
#pragma unroll
          for (int m = 0; m < 4; ++m)
#pragma unroll
            for (int r = 0; r < 4; ++r)
              SH[dcol * VSTR + wr * 64 + m * 16 + kg * 4 + r] = f2bf(acc[m][n][r] + bv);
        }
      }
      __syncthreads();
      {
        const int dcol = tid >> 2, sq = tid & 3;
        const int e = col0 + p * 64 + dcol;
        u16* dst = VT + ((size_t)(nb * NH + (e >> 6)) * HD + (e & 63)) * SEQ + sbase + sq * 32;
#pragma unroll
        for (int i = 0; i < 4; ++i)
          *(short8*)(dst + i * 8) = *(const short8*)(&SH[dcol * VSTR + sq * 32 + i * 8]);
      }
      __syncthreads();
    }
    return;
  }

  // epilogue: row = row0 + wr*64 + m*16 + kg*4 + r ; col = col0 + wc*64 + n*16 + fr
#pragma unroll
  for (int m = 0; m < 4; ++m) {
#pragma unroll
    for (int r = 0; r < 4; ++r) {
      const int rowg = row0 + wr * 64 + m * 16 + kg * 4 + r;
      if (EPI == 1) {
#pragma unroll
        for (int n = 0; n < 4; ++n) {
          const int colg = col0 + wc * 64 + n * 16 + fr;
          Cf[(size_t)rowg * DM + colg] = acc[m][n][r] + bias[colg];
        }
      } else {
        const int l = rowg & (SEQ - 1);
#pragma unroll
        for (int n = 0; n < 4; ++n) {
          const int colg = col0 + wc * 64 + n * 16 + fr;
          const int i = n * 16 + fr;      // position within head (0..63)
          const int fi = i & 31;          // freq index
          const float c = cosT[l * 32 + fi];
          const float s = sinT[l * 32 + fi];
          const float v = acc[m][n][r] + bias[colg];
          const float pv = acc[m][n ^ 2][r] + bias[col0 + wc * 64 + ((n ^ 2) * 16 + fr)];
          const float o = v * c + ((i < 32) ? -pv : pv) * s;
          Cb[(size_t)rowg * DM + colg] = f2bf(o * qscale);
        }
      }
    }
  }
}

// Fused Q/K/V projection. z=0: Q (rope, scaled); z=1: K (rope); z=2: V -> VT (transposed).
__global__ __launch_bounds__(256) void gemm_qkv(
    const u16* __restrict__ Xq, const u16* __restrict__ Xk, const u16* __restrict__ Xv,
    const u16* __restrict__ Wqb, const u16* __restrict__ Wkb, const u16* __restrict__ Wvb,
    const float* __restrict__ bq, const float* __restrict__ bk, const float* __restrict__ bv,
    u16* __restrict__ Qb, u16* __restrict__ Kb, u16* __restrict__ VT,
    const float* __restrict__ cosT, const float* __restrict__ sinT)
{
  __shared__ __align__(16) u16 SH[24576];   // 48 KB: 3 staging buffers; reused as bounce
  const int z = blockIdx.z;
  const int row0 = blockIdx.x * 128, col0 = blockIdx.y * 128;
  if (z == 2) {
    gemm_body<2>(SH, Xv, Wvb, bv, nullptr, nullptr, VT, nullptr, nullptr, 1.0f, row0, col0);
  } else if (z == 0) {
    gemm_body<0>(SH, Xq, Wqb, bq, Qb, nullptr, nullptr, cosT, sinT, 0.125f, row0, col0);
  } else {
    gemm_body<0>(SH, Xk, Wkb, bk, Kb, nullptr, nullptr, cosT, sinT, 1.0f, row0, col0);
  }
}

// Output projection: bf16 A (flash output), f32 out + bias.
__global__ __launch_bounds__(256) void gemm_o(
    const u16* __restrict__ Ob, const u16* __restrict__ Wob,
    const float* __restrict__ bo, float* __restrict__ out)
{
  __shared__ __align__(16) u16 SH[24576];
  gemm_body<1>(SH, Ob, Wob, bo, nullptr, out, nullptr, nullptr, nullptr, 1.0f,
               blockIdx.x * 128, blockIdx.y * 128);
}

// Flash attention, causal, balanced pairing (qbp, 15-qbp), 8 waves x 16 q-rows.
// Swapped QK^T (mfma(K,Q)) -> lane-local softmax; K/V^T staged via XOR-swizzled
// conflict-free LDS; P redistributed through a per-wave LDS strip (no barrier).
__global__ __launch_bounds__(512) void flash_attn(
    const u16* __restrict__ Qp, const u16* __restrict__ Kp,
    const u16* __restrict__ VT, u16* __restrict__ Op)
{
  __shared__ __align__(16) u16 Ks[4096];   // swizzled: chunk c = dc*64 + (s^dc), 16B chunks
  __shared__ __align__(16) u16 Vt[4096];   // swizzled: chunk c = sc*64 + (d^sc)
  __shared__ __align__(16) u16 Pl[9216];   // per-wave P strip: [fr][36 dwords], 144B row stride

  const int tid = threadIdx.x;
  const int lane = tid & 63;
  const int w = tid >> 6;                  // 0..7
  const int fr = lane & 15, rg = lane >> 4;
  const int qbp = blockIdx.x;              // 0..7
  const int h = blockIdx.y, nb = blockIdx.z;

  const size_t headoff = (size_t)nb * SEQ * DM + (size_t)h * HD;      // Q, K, O
  const size_t vthead = (size_t)(nb * NH + h) * HD * SEQ;             // V^T
  const int srow = tid >> 3;   // 0..63 (staging row: s for K, d for V^T)
  const int sch  = tid & 7;    // 16B chunk within row
  u16* Pw = &Pl[w * 1152];

  for (int pass = 0; pass < 2; ++pass) {
    const int qe = pass ? (15 - qbp) : qbp;
    const int KBend = 2 * qe + 2;
    const int qrow0 = qe * 128 + w * 16;
    const int qg = qrow0 + fr;             // this lane's softmax q-row

    short8 qf[2];
#pragma unroll
    for (int ck = 0; ck < 2; ++ck)
      qf[ck] = *(const short8*)(Qp + headoff + (size_t)(qrow0 + fr) * DM + ck * 32 + rg * 8);

    f32x4 accO[4];
#pragma unroll
    for (int df = 0; df < 4; ++df) accO[df] = (f32x4){0.f, 0.f, 0.f, 0.f};
    float m_run = -3e38f, l_run = 0.f;

    // prefetch kb=0 (one 16B chunk of K and V^T per thread)
    short8 kpf = *(const short8*)(Kp + headoff + (size_t)srow * DM + sch * 8);
    short8 vpf = *(const short8*)(VT + vthead + (size_t)srow * SEQ + sch * 8);

    for (int kb = 0; kb < KBend; ++kb) {
      // ---- staged regs -> swizzled LDS (conflict-free) ----
      *(short8*)(&Ks[(sch * 64 + (srow ^ sch)) * 8]) = kpf;
      *(short8*)(&Vt[(sch * 64 + (srow ^ sch)) * 8]) = vpf;
      __syncthreads();
      // ---- issue next tile's global loads (hide under compute) ----
      if (kb + 1 < KBend) {
        kpf = *(const short8*)(Kp + headoff + (size_t)((kb + 1) * 64 + srow) * DM + sch * 8);
        vpf = *(const short8*)(VT + vthead + (size_t)srow * SEQ + (kb + 1) * 64 + sch * 8);
      }

      const bool active = (kb * 64) <= (qrow0 + 15);
      if (active) {
        // ---- QK^T swapped: D[s][q], s = kb*64 + sf*16 + rg*4 + r, q = qg ----
        short8 kf[4][2];
#pragma unroll
        for (int sf = 0; sf < 4; ++sf)
#pragma unroll
          for (int ck = 0; ck < 2; ++ck) {
            const int dc = ck * 4 + rg;
            kf[sf][ck] = *(const short8*)(&Ks[(dc * 64 + ((sf * 16 + fr) ^ dc)) * 8]);
          }
        f32x4 sc_[4];
#pragma unroll
        for (int sf = 0; sf < 4; ++sf) {
          f32x4 z = (f32x4){0.f, 0.f, 0.f, 0.f};
#pragma unroll
          for (int ck = 0; ck < 2; ++ck)
            z = __builtin_amdgcn_mfma_f32_16x16x32_bf16(kf[sf][ck], qf[ck], z, 0, 0, 0);
          sc_[sf] = z;
        }
        // ---- mask + in-register softmax (all 16 values are row qg) ----
        float rowmax = -3e38f;
#pragma unroll
        for (int sf = 0; sf < 4; ++sf)
#pragma unroll
          for (int r = 0; r < 4; ++r) {
            const int sg = kb * 64 + sf * 16 + rg * 4 + r;
            float v = sc_[sf][r];
            v = (sg <= qg) ? v : -3e38f;
            sc_[sf][r] = v;
            rowmax = fmaxf(rowmax, v);
          }
        rowmax = fmaxf(rowmax, __shfl_xor(rowmax, 16, 64));
        rowmax = fmaxf(rowmax, __shfl_xor(rowmax, 32, 64));
        const float mnew = fmaxf(m_run, rowmax);
        const float scl = __expf(m_run - mnew);
        m_run = mnew;
        float psum = 0.f;
#pragma unroll
        for (int sf = 0; sf < 4; ++sf)
#pragma unroll
          for (int r = 0; r < 4; ++r) {
            const float p = __expf(sc_[sf][r] - mnew);
            sc_[sf][r] = p;
            psum += p;
          }
        psum += __shfl_xor(psum, 16, 64);
        psum += __shfl_xor(psum, 32, 64);
        l_run = l_run * scl + psum;
        // ---- rescale accO (its rows are q = qrow0 + rg*4 + r) ----
        const float s0 = __shfl(scl, rg * 4 + 0, 64);
        const float s1 = __shfl(scl, rg * 4 + 1, 64);
        const float s2 = __shfl(scl, rg * 4 + 2, 64);
        const float s3 = __shfl(scl, rg * 4 + 3, 64);
#pragma unroll
        for (int df = 0; df < 4; ++df) {
          accO[df][0] *= s0; accO[df][1] *= s1;
          accO[df][2] *= s2; accO[df][3] *= s3;
        }
        // ---- pack P to bf16 pairs, redistribute via per-wave LDS strip ----
#pragma unroll
        for (int sf = 0; sf < 4; ++sf) {
          u32x2 pv;
          pv[0] = (unsigned)f2bf(sc_[sf][0]) | ((unsigned)f2bf(sc_[sf][1]) << 16);
          pv[1] = (unsigned)f2bf(sc_[sf][2]) | ((unsigned)f2bf(sc_[sf][3]) << 16);
          *(u32x2*)(&Pw[fr * 72 + (sf * 8 + rg * 2) * 2]) = pv;
        }
        short8 pa[2];
#pragma unroll
        for (int ck = 0; ck < 2; ++ck)
          pa[ck] = *(const short8*)(&Pw[fr * 72 + (ck * 16 + rg * 4) * 2]);
        // ---- PV: A = P[q][s], B = V[s][d] from swizzled Vt ----
#pragma unroll
        for (int df = 0; df < 4; ++df)
#pragma unroll
          for (int ck = 0; ck < 2; ++ck) {
            const int sc = ck * 4 + rg;
            const short8 vf = *(const short8*)(&Vt[(sc * 64 + ((df * 16 + fr) ^ sc)) * 8]);
            accO[df] = __builtin_amdgcn_mfma_f32_16x16x32_bf16(pa[ck], vf, accO[df], 0, 0, 0);
          }
      }
      __syncthreads();   // compute reads done before next staging overwrites
    }

    // ---- write O (bf16); accO row q = qrow0 + rg*4 + r ----
    const float l0 = __shfl(l_run, rg * 4 + 0, 64);
    const float l1 = __shfl(l_run, rg * 4 + 1, 64);
    const float l2 = __shfl(l_run, rg * 4 + 2, 64);
    const float l3 = __shfl(l_run, rg * 4 + 3, 64);
#pragma unroll
    for (int df = 0; df < 4; ++df) {
      const int d = df * 16 + fr;
      Op[headoff + (size_t)(qrow0 + rg * 4 + 0) * DM + d] = f2bf(accO[df][0] / l0);
      Op[headoff + (size_t)(qrow0 + rg * 4 + 1) * DM + d] = f2bf(accO[df][1] / l1);
      Op[headoff + (size_t)(qrow0 + rg * 4 + 2) * DM + d] = f2bf(accO[df][2] / l2);
      Op[headoff + (size_t)(qrow0 + rg * 4 + 3) * DM + d] = f2bf(accO[df][3] / l3);
    }
  }
}

extern "C" void kernel_launch(void* const* d_in, const int* in_sizes, int n_in,
                              void* d_out, int out_size, void* d_ws, size_t ws_size,
                              hipStream_t stream) {
  (void)in_sizes; (void)n_in; (void)out_size; (void)ws_size;
  const float* queries = (const float*)d_in[0];
  const float* keys    = (const float*)d_in[1];
  const float* values  = (const float*)d_in[2];
  const float* Wq = (const float*)d_in[3];
  const float* bq = (const float*)d_in[4];
  const float* Wk = (const float*)d_in[5];
  const float* bk = (const float*)d_in[6];
  const float* Wv = (const float*)d_in[7];
  const float* bv = (const float*)d_in[8];
  const float* Wo = (const float*)d_in[9];
  const float* bo = (const float*)d_in[10];
  float* out = (float*)d_out;

  char* ws = (char*)d_ws;
  const size_t MB = 1u << 20;
  u16* Qb  = (u16*)(ws);
  u16* Kb  = (u16*)(ws + 8 * MB);
  u16* VTg = (u16*)(ws + 16 * MB);
  u16* Xq  = (u16*)(ws + 24 * MB);   // Ob aliases Xq (Xq dead after gemm_qkv)
  u16* Ob  = Xq;
  u16* Xk  = (u16*)(ws + 32 * MB);
  u16* Xv  = (u16*)(ws + 40 * MB);
  u16* Wqb = (u16*)(ws + 48 * MB);
  u16* Wkb = (u16*)(ws + 50 * MB);
  u16* Wvb = (u16*)(ws + 52 * MB);
  u16* Wob = (u16*)(ws + 54 * MB);
  float* cosT = (float*)(ws + 56 * MB);
  float* sinT = (float*)(ws + 56 * MB + 256 * 1024);

  conv_all<<<dim3(2048, 1, 8), 256, 0, stream>>>(
      queries, keys, values, Wq, Wk, Wv, Wo,
      Xq, Xk, Xv, Wqb, Wkb, Wvb, Wob, cosT, sinT);
  gemm_qkv<<<dim3(MROWS / 128, DM / 128, 3), 256, 0, stream>>>(
      Xq, Xk, Xv, Wqb, Wkb, Wvb, bq, bk, bv, Qb, Kb, VTg, cosT, sinT);
  flash_attn<<<dim3(SEQ / 256, NH, NB2), 512, 0, stream>>>(Qb, Kb, VTg, Ob);
  gemm_o<<<dim3(MROWS / 128, DM / 128), 256, 0, stream>>>(Ob, Wob, bo, out);
}